// Round 8
// baseline (256.910 us; speedup 1.0000x reference)
//
#include <hip/hip_runtime.h>
#include <math.h>

constexpr int CB  = 16;
constexpr int CN  = 1024;
constexpr int CD  = 512;
constexpr int KM1 = 7;      // K_MAX + 1 candidate slots per batch
constexpr int RB  = 16;     // rows per k_attn block

typedef __attribute__((ext_vector_type(8))) short bf8;
typedef __attribute__((ext_vector_type(4))) float f32x4;
typedef __attribute__((ext_vector_type(4))) unsigned short us4;

__device__ inline float bf2f(unsigned short u) {
    union { unsigned int i; float f; } v; v.i = ((unsigned)u) << 16; return v.f;
}
__device__ inline unsigned short f2bf(float f) {
    union { unsigned int i; float f; } v; v.f = f;
    unsigned r = v.i + 0x7FFFu + ((v.i >> 16) & 1u);
    return (unsigned short)(r >> 16);
}
__device__ inline bf8 pack8(float4 x, float4 y) {
    bf8 r;
    r[0] = (short)f2bf(x.x); r[1] = (short)f2bf(x.y);
    r[2] = (short)f2bf(x.z); r[3] = (short)f2bf(x.w);
    r[4] = (short)f2bf(y.x); r[5] = (short)f2bf(y.y);
    r[6] = (short)f2bf(y.z); r[7] = (short)f2bf(y.w);
    return r;
}

// ---------------------------------------------------------------------------
// Kernel PRE (fused): blocks 0..15 = per-batch top-7; blocks 16..143 =
// transpose Wk/Wv -> bf16 WT[c][k]; block 144 = compute K scalar.
// ---------------------------------------------------------------------------
__global__ __launch_bounds__(256) void k_pre(
    const float* __restrict__ dist, const float* __restrict__ speed,
    const float* __restrict__ Wk, const float* __restrict__ Wv,
    int* __restrict__ Kout,
    int* __restrict__ candIdx, float* __restrict__ candDist,
    unsigned short* __restrict__ WkT, unsigned short* __restrict__ WvT) {
    int t = threadIdx.x;
    int bid = blockIdx.x;

    if (bid < 16) {
        __shared__ float sd[64 * KM1];
        __shared__ int   si[64 * KM1];
        int b = bid;
        if (t < 64) {
            float d7[KM1]; int i7[KM1];
#pragma unroll
            for (int j = 0; j < KM1; j++) { d7[j] = 3.4e38f; i7[j] = -1; }
            for (int i = t; i < CN; i += 64) {
                float d = dist[b * CN + i];
                if (d < d7[KM1 - 1]) {
                    int p = KM1 - 1;
                    while (p > 0 && d7[p - 1] > d) {
                        d7[p] = d7[p - 1]; i7[p] = i7[p - 1]; p--;
                    }
                    d7[p] = d; i7[p] = i;
                }
            }
            for (int j = 0; j < KM1; j++) { sd[t * KM1 + j] = d7[j]; si[t * KM1 + j] = i7[j]; }
        }
        __syncthreads();
        if (t == 0) {
            float m7[KM1]; int mi[KM1];
            for (int j = 0; j < KM1; j++) { m7[j] = 3.4e38f; mi[j] = -1; }
            for (int e = 0; e < 64 * KM1; e++) {
                float d = sd[e];
                if (d < m7[KM1 - 1]) {
                    int ii = si[e];
                    int p = KM1 - 1;
                    while (p > 0 && m7[p - 1] > d) {
                        m7[p] = m7[p - 1]; mi[p] = mi[p - 1]; p--;
                    }
                    m7[p] = d; mi[p] = ii;
                }
            }
            for (int j = 0; j < KM1; j++) {
                candIdx[b * KM1 + j]  = mi[j];
                candDist[b * KM1 + j] = m7[j];
            }
        }
        return;
    }
    if (bid < 144) {
        __shared__ unsigned short tile[64][68];
        int b2 = bid - 16;
        int kt = b2 & 7, ct = (b2 >> 3) & 7, mat = b2 >> 6;
        const float* W = mat ? Wv : Wk;
        unsigned short* WT = mat ? WvT : WkT;
        int k0 = kt * 64, c0 = ct * 64;
#pragma unroll
        for (int p = 0; p < 4; p++) {
            int kr = p * 16 + (t >> 4);
            int cc = (t & 15) * 4;
            float4 v = *(const float4*)(W + (size_t)(k0 + kr) * CD + c0 + cc);
            tile[kr][cc + 0] = f2bf(v.x);
            tile[kr][cc + 1] = f2bf(v.y);
            tile[kr][cc + 2] = f2bf(v.z);
            tile[kr][cc + 3] = f2bf(v.w);
        }
        __syncthreads();
#pragma unroll
        for (int p = 0; p < 4; p++) {
            int cr = p * 16 + (t >> 4);
            int kk = (t & 15) * 4;
            us4 o;
            o.x = tile[kk + 0][cr];
            o.y = tile[kk + 1][cr];
            o.z = tile[kk + 2][cr];
            o.w = tile[kk + 3][cr];
            *(us4*)(WT + (size_t)(c0 + cr) * CD + k0 + kk) = o;
        }
        return;
    }
    {
        __shared__ int red[256];
        int cnt = 0;
        for (int i = t; i < CB * CN; i += 256) cnt += (dist[i] < 20.0f) ? 1 : 0;
        red[t] = cnt;
        __syncthreads();
        for (int s = 128; s > 0; s >>= 1) {
            if (t < s) red[t] += red[t + s];
            __syncthreads();
        }
        if (t == 0) {
            float ss = 0.f;
            for (int i = 0; i < CB; i++) ss += speed[i];
            int K = 4;
            if (ss / (float)CB > 15.0f) K = (K + 1 > 6) ? 6 : K + 1;
            float density = (float)red[0] / (float)(CB * CN);
            if (density > 0.5f) K = (K + 1 > 6) ? 6 : K + 1;
            if (K > CN - 1) K = CN - 1;
            if (K < 0) K = 0;
            *Kout = K;
        }
    }
}

// ---------------------------------------------------------------------------
// Kernel MID (fused candkv + Y): one block per batch.
//   1) Stage Xc[7x512] bf16 in LDS.
//   2) MFMA: Kc = Xc@Wk + bk -> bf16 LDS (no global round-trip);
//            Vc = Xc@Wv + bv -> global f32.
//   3) S0[b][mat][m][h] = sum_{c in head h} bias[c]*Kc[m][c]  (from bf16 Kc)
//   4) MFMA: Y[b][mat*56+m*8+h][k] = sum_{c in head h} W[k][c]*Kc[m][c]
// ---------------------------------------------------------------------------
__global__ __launch_bounds__(256) void k_mid(
    const float* __restrict__ X,
    const unsigned short* __restrict__ WkT, const float* __restrict__ bk,
    const unsigned short* __restrict__ WvT, const float* __restrict__ bv,
    const float* __restrict__ Wq, const float* __restrict__ bq,
    const float* __restrict__ Weq, const float* __restrict__ beq,
    const int* __restrict__ candIdx,
    float* __restrict__ Vc, float* __restrict__ S0,
    unsigned short* __restrict__ Y) {
    int b = blockIdx.x;
    __shared__ unsigned short sA[16][520];     // Xc bf16
    __shared__ unsigned short sKcb[16][520];   // Kc bf16 (rows 7..15 zero)
    int t = threadIdx.x;

    for (int i = t; i < 16 * 128; i += 256) {
        int m = i >> 7, c4 = i & 127;
        float4 xv = {0.f, 0.f, 0.f, 0.f};
        if (m < KM1)
            xv = *(const float4*)(X + (size_t)(b * CN + candIdx[b * KM1 + m]) * CD + c4 * 4);
        us4 o; o.x = f2bf(xv.x); o.y = f2bf(xv.y); o.z = f2bf(xv.z); o.w = f2bf(xv.w);
        *(us4*)&sA[m][c4 * 4] = o;
    }
    __syncthreads();

    int w = t >> 6, lane = t & 63, lr = lane & 15, kg = lane >> 4;
    // ---- Kc (-> LDS bf16) and Vc (-> global f32); each wave owns 128 cols
#pragma unroll
    for (int mat = 0; mat < 2; mat++) {
        const unsigned short* WT = mat ? WvT : WkT;
        const float* bias = mat ? bv : bk;
#pragma unroll
        for (int i = 0; i < 8; i++) {
            int c = w * 128 + i * 16 + lr;
            const unsigned short* wtp = WT + (size_t)c * CD + kg * 8;
            f32x4 acc = {0.f, 0.f, 0.f, 0.f};
#pragma unroll
            for (int s = 0; s < 16; s++) {
                bf8 bfr = *(const bf8*)(wtp + s * 32);
                bf8 a   = *(const bf8*)&sA[lr][s * 32 + kg * 8];
                acc = __builtin_amdgcn_mfma_f32_16x16x32_bf16(a, bfr, acc, 0, 0, 0);
            }
            float bv_ = bias[c];
#pragma unroll
            for (int q = 0; q < 4; q++) {
                int m = kg * 4 + q;
                float val = (m < KM1) ? (acc[q] + bv_) : 0.f;
                if (mat == 0) sKcb[m][c] = f2bf(val);
                else if (m < KM1) Vc[(size_t)(b * KM1 + m) * CD + c] = val;
            }
        }
    }
    __syncthreads();

    // ---- S0 (112 threads: mat x m x h)
    if (t < 112) {
        int mat = t / 56, rem = t - mat * 56, m = rem >> 3, h = rem & 7;
        const float* bias = mat ? beq : bq;
        float s = 0.f;
        int c0 = h * 64;
        for (int c = c0; c < c0 + 64; c++) s = fmaf(bias[c], bf2f(sKcb[m][c]), s);
        S0[((b * 2 + mat) * KM1 + m) * 8 + h] = s;
    }

    // ---- Y: each wave owns 4 (mat,h) units; 32 n-tiles each
#pragma unroll
    for (int u = 0; u < 4; u++) {
        int unit = w * 4 + u;
        int mat = unit >> 3, h = unit & 7;
        const float* W = mat ? Weq : Wq;
        unsigned short* Yb = Y + ((size_t)(b * 112) + mat * 56) * 512;
        bf8 a0 = *(const bf8*)&sKcb[lr][h * 64 + kg * 8];
        bf8 a1 = *(const bf8*)&sKcb[lr][h * 64 + 32 + kg * 8];
#pragma unroll 4
        for (int nt = 0; nt < 32; nt++) {
            int n0 = nt * 16;
            const float* wp = W + (size_t)(n0 + lr) * CD + h * 64 + kg * 8;
            float4 f0 = *(const float4*)(wp);
            float4 f1 = *(const float4*)(wp + 4);
            float4 f2 = *(const float4*)(wp + 32);
            float4 f3 = *(const float4*)(wp + 36);
            f32x4 acc = {0.f, 0.f, 0.f, 0.f};
            acc = __builtin_amdgcn_mfma_f32_16x16x32_bf16(a0, pack8(f0, f1), acc, 0, 0, 0);
            acc = __builtin_amdgcn_mfma_f32_16x16x32_bf16(a1, pack8(f2, f3), acc, 0, 0, 0);
            int k_out = n0 + lr;
#pragma unroll
            for (int q = 0; q < 4; q++) {
                int m = kg * 4 + q;
                if (m < KM1)
                    Yb[(size_t)(m * 8 + h) * 512 + k_out] = f2bf(acc[q]);
            }
        }
    }
}

// ---------------------------------------------------------------------------
// Kernel attn: fused scores (MFMA vs Y) + bias MLP + softmax + PV + residual
// + LN.  Block = 16 rows of one batch; 256 threads; grid = 16*64 = 1024
// (4 blocks/CU).  X read from global (L2/L3-hot); V staged in LDS.
// ---------------------------------------------------------------------------
__global__ __launch_bounds__(256) void k_attn(
    const float* __restrict__ X, const float* __restrict__ dist,
    const float* __restrict__ mask,
    const float* __restrict__ Wd1, const float* __restrict__ bd1,
    const float* __restrict__ Wd2, const float* __restrict__ bd2,
    const float* __restrict__ lng, const float* __restrict__ lnb,
    const int* __restrict__ Kp, const int* __restrict__ candIdx,
    const float* __restrict__ candDist,
    const float* __restrict__ Vc, const float* __restrict__ S0,
    const unsigned short* __restrict__ Y,
    float* __restrict__ out) {

    __shared__ float sS[RB][116];              // raw scores (112 cols used)
    __shared__ unsigned short sVc[KM1][520];   // V rows bf16
    __shared__ float sW[RB][8][6];             // softmax weights
    __shared__ float sBias[RB][6][4][8];       // bias MLP partials (4 quarters)
    __shared__ int   snbr[RB][6];
    __shared__ float skd[RB][6];
    __shared__ float srd[RB];
    __shared__ float sE[RB];
    __shared__ float sS0[112];

    int t = threadIdx.x;
    int b = blockIdx.x >> 6, rblk = blockIdx.x & 63;
    int row0 = b * CN + rblk * RB;   // global flat row
    int K = *Kp;

    // ---- phase A: staging (V rows + per-row metadata)
    for (int idx = t; idx < KM1 * 128; idx += 256) {
        int m = idx >> 7, c4 = idx & 127;
        float4 vv = *(const float4*)(Vc + ((size_t)(b * KM1 + m)) * CD + c4 * 4);
        us4 o; o.x = f2bf(vv.x); o.y = f2bf(vv.y); o.z = f2bf(vv.z); o.w = f2bf(vv.w);
        *(us4*)&sVc[m][c4 * 4] = o;
    }
    if (t < 112) sS0[t] = S0[b * 112 + t];
    if (t < RB) {
        int i = rblk * RB + t;
        sE[t]  = mask[b * CN + i];
        srd[t] = dist[b * CN + i];
        int cnt = 0;
        for (int m = 0; m <= K && cnt < K; m++) {
            int c = candIdx[b * KM1 + m];
            if (c != i) { snbr[t][cnt] = m; skd[t][cnt] = candDist[b * KM1 + m]; cnt++; }
        }
    }
    __syncthreads();

    // ---- phase B1: score MFMA  S[r][n] = X_r . Y_n  (K=512), X from global
    {
        int w = t >> 6, lane = t & 63, lr = lane & 15, kg = lane >> 4;
        f32x4 acc0 = {0.f, 0.f, 0.f, 0.f}, acc1 = acc0;
        bool has2 = (w < 3);
        const unsigned short* Yb = Y + (size_t)b * 112 * 512;
        const unsigned short* y0p = Yb + (size_t)(w * 16 + lr) * 512 + kg * 8;
        const unsigned short* y1p = Yb + (size_t)((w + 4) * 16 + lr) * 512 + kg * 8;
        const float* x0 = X + (size_t)(row0 + lr) * CD + kg * 8;
#pragma unroll
        for (int s = 0; s < 16; s++) {
            float4 xa = *(const float4*)(x0 + s * 32);
            float4 xb = *(const float4*)(x0 + s * 32 + 4);
            bf8 a0 = pack8(xa, xb);
            bf8 b0 = *(const bf8*)&y0p[s * 32];
            acc0 = __builtin_amdgcn_mfma_f32_16x16x32_bf16(a0, b0, acc0, 0, 0, 0);
            if (has2) {
                bf8 b1 = *(const bf8*)&y1p[s * 32];
                acc1 = __builtin_amdgcn_mfma_f32_16x16x32_bf16(a0, b1, acc1, 0, 0, 0);
            }
        }
        int n0 = w * 16 + lr;
#pragma unroll
        for (int q = 0; q < 4; q++) sS[kg * 4 + q][n0] = acc0[q];
        if (has2) {
            int n1 = (w + 4) * 16 + lr;
#pragma unroll
            for (int q = 0; q < 4; q++) sS[kg * 4 + q][n1] = acc1[q];
        }
    }
    // ---- phase B2: bias MLP (4 threads per (r,k) pair, quarter hidden each)
    {
        int quarter = t & 3;
        int j0 = quarter * 32;
        for (int pid = t >> 2; pid < RB * K; pid += 64) {
            int r = pid / K, k = pid - r * K;
            float qd = srd[r], kd = skd[r][k];
            float bacc[8];
#pragma unroll
            for (int h = 0; h < 8; h++) bacc[h] = 0.f;
            for (int j = j0; j < j0 + 32; j++) {
                float hid = fmaf(qd, Wd1[j], fmaf(kd, Wd1[128 + j], bd1[j]));
                hid = fmaxf(hid, 0.f);
                float4 wa = *(const float4*)(Wd2 + j * 8);
                float4 wb = *(const float4*)(Wd2 + j * 8 + 4);
                bacc[0] = fmaf(hid, wa.x, bacc[0]);
                bacc[1] = fmaf(hid, wa.y, bacc[1]);
                bacc[2] = fmaf(hid, wa.z, bacc[2]);
                bacc[3] = fmaf(hid, wa.w, bacc[3]);
                bacc[4] = fmaf(hid, wb.x, bacc[4]);
                bacc[5] = fmaf(hid, wb.y, bacc[5]);
                bacc[6] = fmaf(hid, wb.z, bacc[6]);
                bacc[7] = fmaf(hid, wb.w, bacc[7]);
            }
#pragma unroll
            for (int h = 0; h < 8; h++) sBias[r][k][quarter][h] = bacc[h];
        }
    }
    __syncthreads();

    // ---- phase C: blend ego/non-ego scores, multiply bias
    {
        int tot = RB * 8 * K;
        for (int id = t; id < tot; id += 256) {
            int k = id % K; int rh = id / K; int r = rh >> 3, h = rh & 7;
            int m = snbr[r][k];
            float e = sE[r];
            float scq = sS[r][m * 8 + h]      + sS0[m * 8 + h];
            float sce = sS[r][56 + m * 8 + h] + sS0[56 + m * 8 + h];
            float sc = (1.f - e) * scq + e * sce;
            float bias = sBias[r][k][0][h] + sBias[r][k][1][h]
                       + sBias[r][k][2][h] + sBias[r][k][3][h] + bd2[h];
            sW[r][h][k] = sc * 0.125f * bias;
        }
    }
    __syncthreads();

    // ---- phase D: softmax over k (128 tasks)
    if (t < RB * 8) {
        int r = t >> 3, h = t & 7;
        float mx = -3.4e38f;
        for (int k = 0; k < K; k++) mx = fmaxf(mx, sW[r][h][k]);
        float sum = 0.f;
        for (int k = 0; k < K; k++) {
            float w0 = __expf(sW[r][h][k] - mx);
            sW[r][h][k] = w0;
            sum += w0;
        }
        float inv = 1.f / sum;
        for (int k = 0; k < K; k++) sW[r][h][k] *= inv;
    }
    __syncthreads();

    // ---- phase E: PV + residual + LayerNorm (16 threads per row, h = j)
    {
        int r = t >> 4, tr = t & 15;
        const float* xrow = X + (size_t)(row0 + r) * CD;
        float4 vals[8];
        float sum = 0.f, sq = 0.f;
#pragma unroll
        for (int j = 0; j < 8; j++) {
            int d = tr * 4 + j * 64;
            float ax = 0.f, ay = 0.f, az = 0.f, aw = 0.f;
            for (int k = 0; k < K; k++) {
                int m = snbr[r][k];
                float wgt = sW[r][j][k];
                us4 vv = *(const us4*)&sVc[m][d];
                ax = fmaf(wgt, bf2f(vv.x), ax);
                ay = fmaf(wgt, bf2f(vv.y), ay);
                az = fmaf(wgt, bf2f(vv.z), az);
                aw = fmaf(wgt, bf2f(vv.w), aw);
            }
            float4 xv = *(const float4*)(xrow + d);
            float4 v;
            v.x = xv.x + ax; v.y = xv.y + ay; v.z = xv.z + az; v.w = xv.w + aw;
            vals[j] = v;
            sum += v.x + v.y + v.z + v.w;
            sq = fmaf(v.x, v.x, sq); sq = fmaf(v.y, v.y, sq);
            sq = fmaf(v.z, v.z, sq); sq = fmaf(v.w, v.w, sq);
        }
        sum += __shfl_xor(sum, 1, 16); sq += __shfl_xor(sq, 1, 16);
        sum += __shfl_xor(sum, 2, 16); sq += __shfl_xor(sq, 2, 16);
        sum += __shfl_xor(sum, 4, 16); sq += __shfl_xor(sq, 4, 16);
        sum += __shfl_xor(sum, 8, 16); sq += __shfl_xor(sq, 8, 16);
        float mu  = sum * (1.f / 512.f);
        float var = sq * (1.f / 512.f) - mu * mu;
        float inv = rsqrtf(var + 1e-5f);
        float* orow = out + (size_t)(row0 + r) * CD;
#pragma unroll
        for (int j = 0; j < 8; j++) {
            int d = tr * 4 + j * 64;
            float4 g  = *(const float4*)(lng + d);
            float4 bb = *(const float4*)(lnb + d);
            float4 v = vals[j];
            float4 o;
            o.x = (v.x - mu) * inv * g.x + bb.x;
            o.y = (v.y - mu) * inv * g.y + bb.y;
            o.z = (v.z - mu) * inv * g.z + bb.z;
            o.w = (v.w - mu) * inv * g.w + bb.w;
            *(float4*)(orow + d) = o;
        }
    }
}

// ---------------------------------------------------------------------------
extern "C" void kernel_launch(void* const* d_in, const int* in_sizes, int n_in,
                              void* d_out, int out_size, void* d_ws, size_t ws_size,
                              hipStream_t stream) {
    (void)in_sizes; (void)n_in; (void)out_size; (void)ws_size;
    const float* X     = (const float*)d_in[0];
    const float* dist  = (const float*)d_in[1];
    const float* mask  = (const float*)d_in[2];
    const float* speed = (const float*)d_in[3];
    const float* Wq    = (const float*)d_in[4];
    const float* bq    = (const float*)d_in[5];
    const float* Wk    = (const float*)d_in[6];
    const float* bk    = (const float*)d_in[7];
    const float* Wv    = (const float*)d_in[8];
    const float* bv    = (const float*)d_in[9];
    const float* Weq   = (const float*)d_in[10];
    const float* beq   = (const float*)d_in[11];
    const float* Wd1   = (const float*)d_in[16];
    const float* bd1   = (const float*)d_in[17];
    const float* Wd2   = (const float*)d_in[18];
    const float* bd2   = (const float*)d_in[19];
    const float* lng   = (const float*)d_in[20];
    const float* lnb   = (const float*)d_in[21];
    float* out = (float*)d_out;

    char* ws = (char*)d_ws;
    int*   Kp       = (int*)(ws);
    int*   candIdx  = (int*)(ws + 256);
    float* candDist = (float*)(ws + 1024);
    float* S0       = (float*)(ws + 2048);                 // 7168 B
    float* Vc       = (float*)(ws + 245760);               // 229376 B
    unsigned short* Y   = (unsigned short*)(ws + 475136);  // 1835008 B
    unsigned short* WkT = (unsigned short*)(ws + 2310144); // 524288 B
    unsigned short* WvT = (unsigned short*)(ws + 2834432); // 524288 B

    k_pre<<<145, 256, 0, stream>>>(dist, speed, Wk, Wv, Kp, candIdx, candDist, WkT, WvT);
    k_mid<<<CB, 256, 0, stream>>>(X, WkT, bk, WvT, bv, Wq, bq, Weq, beq,
                                  candIdx, Vc, S0, Y);
    k_attn<<<CB * (CN / RB), 256, 0, stream>>>(X, dist, mask, Wd1, bd1, Wd2, bd2, lng, lnb,
                                               Kp, candIdx, candDist, Vc, S0, Y, out);
}

// Round 9
// 137.222 us; speedup vs baseline: 1.8722x; 1.8722x over previous
//
#include <hip/hip_runtime.h>
#include <math.h>

constexpr int CB  = 16;
constexpr int CN  = 1024;
constexpr int CD  = 512;
constexpr int KM1 = 7;      // K_MAX + 1 candidate slots per batch
constexpr int RB  = 16;     // rows per k_attn block

typedef __attribute__((ext_vector_type(8))) short bf8;
typedef __attribute__((ext_vector_type(4))) float f32x4;
typedef __attribute__((ext_vector_type(4))) unsigned short us4;

__device__ inline float bf2f(unsigned short u) {
    union { unsigned int i; float f; } v; v.i = ((unsigned)u) << 16; return v.f;
}
__device__ inline unsigned short f2bf(float f) {
    union { unsigned int i; float f; } v; v.f = f;
    unsigned r = v.i + 0x7FFFu + ((v.i >> 16) & 1u);
    return (unsigned short)(r >> 16);
}
__device__ inline bf8 pack8(float4 x, float4 y) {
    bf8 r;
    r[0] = (short)f2bf(x.x); r[1] = (short)f2bf(x.y);
    r[2] = (short)f2bf(x.z); r[3] = (short)f2bf(x.w);
    r[4] = (short)f2bf(y.x); r[5] = (short)f2bf(y.y);
    r[6] = (short)f2bf(y.z); r[7] = (short)f2bf(y.w);
    return r;
}

// ---------------------------------------------------------------------------
// Kernel PRE (fused): blocks 0..15 = per-batch top-7; blocks 16..143 =
// transpose Wk/Wv -> bf16 WT[c][k]; block 144 = compute K scalar.
// ---------------------------------------------------------------------------
__global__ __launch_bounds__(256) void k_pre(
    const float* __restrict__ dist, const float* __restrict__ speed,
    const float* __restrict__ Wk, const float* __restrict__ Wv,
    int* __restrict__ Kout,
    int* __restrict__ candIdx, float* __restrict__ candDist,
    unsigned short* __restrict__ WkT, unsigned short* __restrict__ WvT) {
    int t = threadIdx.x;
    int bid = blockIdx.x;

    if (bid < 16) {
        __shared__ float sd[64 * KM1];
        __shared__ int   si[64 * KM1];
        int b = bid;
        if (t < 64) {
            float d7[KM1]; int i7[KM1];
#pragma unroll
            for (int j = 0; j < KM1; j++) { d7[j] = 3.4e38f; i7[j] = -1; }
            for (int i = t; i < CN; i += 64) {
                float d = dist[b * CN + i];
                if (d < d7[KM1 - 1]) {
                    int p = KM1 - 1;
                    while (p > 0 && d7[p - 1] > d) {
                        d7[p] = d7[p - 1]; i7[p] = i7[p - 1]; p--;
                    }
                    d7[p] = d; i7[p] = i;
                }
            }
            for (int j = 0; j < KM1; j++) { sd[t * KM1 + j] = d7[j]; si[t * KM1 + j] = i7[j]; }
        }
        __syncthreads();
        if (t == 0) {
            float m7[KM1]; int mi[KM1];
            for (int j = 0; j < KM1; j++) { m7[j] = 3.4e38f; mi[j] = -1; }
            for (int e = 0; e < 64 * KM1; e++) {
                float d = sd[e];
                if (d < m7[KM1 - 1]) {
                    int ii = si[e];
                    int p = KM1 - 1;
                    while (p > 0 && m7[p - 1] > d) {
                        m7[p] = m7[p - 1]; mi[p] = mi[p - 1]; p--;
                    }
                    m7[p] = d; mi[p] = ii;
                }
            }
            for (int j = 0; j < KM1; j++) {
                candIdx[b * KM1 + j]  = mi[j];
                candDist[b * KM1 + j] = m7[j];
            }
        }
        return;
    }
    if (bid < 144) {
        __shared__ unsigned short tile[64][68];
        int b2 = bid - 16;
        int kt = b2 & 7, ct = (b2 >> 3) & 7, mat = b2 >> 6;
        const float* W = mat ? Wv : Wk;
        unsigned short* WT = mat ? WvT : WkT;
        int k0 = kt * 64, c0 = ct * 64;
#pragma unroll
        for (int p = 0; p < 4; p++) {
            int kr = p * 16 + (t >> 4);
            int cc = (t & 15) * 4;
            float4 v = *(const float4*)(W + (size_t)(k0 + kr) * CD + c0 + cc);
            tile[kr][cc + 0] = f2bf(v.x);
            tile[kr][cc + 1] = f2bf(v.y);
            tile[kr][cc + 2] = f2bf(v.z);
            tile[kr][cc + 3] = f2bf(v.w);
        }
        __syncthreads();
#pragma unroll
        for (int p = 0; p < 4; p++) {
            int cr = p * 16 + (t >> 4);
            int kk = (t & 15) * 4;
            us4 o;
            o.x = tile[kk + 0][cr];
            o.y = tile[kk + 1][cr];
            o.z = tile[kk + 2][cr];
            o.w = tile[kk + 3][cr];
            *(us4*)(WT + (size_t)(c0 + cr) * CD + k0 + kk) = o;
        }
        return;
    }
    {
        __shared__ int red[256];
        int cnt = 0;
        for (int i = t; i < CB * CN; i += 256) cnt += (dist[i] < 20.0f) ? 1 : 0;
        red[t] = cnt;
        __syncthreads();
        for (int s = 128; s > 0; s >>= 1) {
            if (t < s) red[t] += red[t + s];
            __syncthreads();
        }
        if (t == 0) {
            float ss = 0.f;
            for (int i = 0; i < CB; i++) ss += speed[i];
            int K = 4;
            if (ss / (float)CB > 15.0f) K = (K + 1 > 6) ? 6 : K + 1;
            float density = (float)red[0] / (float)(CB * CN);
            if (density > 0.5f) K = (K + 1 > 6) ? 6 : K + 1;
            if (K > CN - 1) K = CN - 1;
            if (K < 0) K = 0;
            *Kout = K;
        }
    }
}

// ---------------------------------------------------------------------------
// Kernel C (MFMA): K/V projections of the 7 candidate rows per batch.
// ---------------------------------------------------------------------------
__global__ __launch_bounds__(256) void k_candkv(
    const float* __restrict__ X,
    const unsigned short* __restrict__ WkT, const float* __restrict__ bk,
    const unsigned short* __restrict__ WvT, const float* __restrict__ bv,
    const int* __restrict__ candIdx,
    float* __restrict__ Kc, float* __restrict__ Vc) {
    int b   = blockIdx.x;
    int ny  = blockIdx.y;
    int mat = blockIdx.z;
    const unsigned short* WT = mat ? WvT : WkT;
    const float* bias = mat ? bv : bk;
    float*       Out  = mat ? Vc : Kc;

    __shared__ unsigned short sA[16][520];
    int t = threadIdx.x;
    for (int i = t; i < 16 * 128; i += 256) {
        int m = i >> 7, c4 = i & 127;
        float4 xv = {0.f, 0.f, 0.f, 0.f};
        if (m < KM1)
            xv = *(const float4*)(X + (size_t)(b * CN + candIdx[b * KM1 + m]) * CD + c4 * 4);
        us4 o; o.x = f2bf(xv.x); o.y = f2bf(xv.y); o.z = f2bf(xv.z); o.w = f2bf(xv.w);
        *(us4*)&sA[m][c4 * 4] = o;
    }
    __syncthreads();

    int w = t >> 6, lane = t & 63, lr = lane & 15, kg = lane >> 4;
    int c = ny * 64 + w * 16 + lr;
    const unsigned short* wtp = WT + (size_t)c * CD + kg * 8;
    f32x4 acc = {0.f, 0.f, 0.f, 0.f};
#pragma unroll
    for (int s = 0; s < 16; s++) {
        bf8 bfr = *(const bf8*)(wtp + s * 32);
        bf8 a   = *(const bf8*)&sA[lr][s * 32 + kg * 8];
        acc = __builtin_amdgcn_mfma_f32_16x16x32_bf16(a, bfr, acc, 0, 0, 0);
    }
    float bv_ = bias[c];
#pragma unroll
    for (int q = 0; q < 4; q++) {
        int m = kg * 4 + q;
        if (m < KM1)
            Out[(size_t)(b * KM1 + m) * CD + c] = acc[q] + bv_;
    }
}

// ---------------------------------------------------------------------------
// Kernel Y (MFMA): per block (b,h,half):
//   Y[b][mat*56 + m*8 + h][k] = sum_{c in head h} W[k][c] * Kc[b][m][c]
//   S0[b][mat][m][h] = sum_{c in head} bias[c]*Kc[b][m][c]  (half==0 only)
// ---------------------------------------------------------------------------
__global__ __launch_bounds__(256) void k_Y(
    const float* __restrict__ Wq, const float* __restrict__ bq,
    const float* __restrict__ Weq, const float* __restrict__ beq,
    const float* __restrict__ Kc, float* __restrict__ S0,
    unsigned short* __restrict__ Y) {
    int b = blockIdx.x >> 3, h = blockIdx.x & 7;
    int half = blockIdx.y;
    __shared__ unsigned short sA[16][64];
    __shared__ float sKf[KM1][64];
    int t = threadIdx.x;
    for (int i = t; i < 16 * 64; i += 256) {
        int m = i >> 6, c = i & 63;
        float v = (m < KM1) ? Kc[((size_t)(b * KM1 + m)) * CD + h * 64 + c] : 0.f;
        sA[m][c] = f2bf(v);
        if (m < KM1) sKf[m][c] = v;
    }
    __syncthreads();
    if (half == 0 && t < 14) {
        int mat = t / 7, m = t % 7;
        const float* bias = mat ? beq : bq;
        float s = 0.f;
        for (int c = 0; c < 64; c++) s = fmaf(bias[h * 64 + c], sKf[m][c], s);
        S0[((b * 2 + mat) * KM1 + m) * 8 + h] = s;
    }
    int w = t >> 6, lane = t & 63, lr = lane & 15, kg = lane >> 4;
    bf8 a0 = *(const bf8*)&sA[lr][kg * 8];
    bf8 a1 = *(const bf8*)&sA[lr][32 + kg * 8];
#pragma unroll
    for (int mat = 0; mat < 2; mat++) {
        const float* W = mat ? Weq : Wq;
        unsigned short* Yb = Y + ((size_t)(b * 112) + mat * 56) * 512;
#pragma unroll
        for (int nt = 0; nt < 4; nt++) {
            int n0 = (half * 16 + w * 4 + nt) * 16;   // k_out tile base
            const float* wp = W + (size_t)(n0 + lr) * CD + h * 64 + kg * 8;
            float4 f0 = *(const float4*)(wp);
            float4 f1 = *(const float4*)(wp + 4);
            float4 f2 = *(const float4*)(wp + 32);
            float4 f3 = *(const float4*)(wp + 36);
            f32x4 acc = {0.f, 0.f, 0.f, 0.f};
            acc = __builtin_amdgcn_mfma_f32_16x16x32_bf16(a0, pack8(f0, f1), acc, 0, 0, 0);
            acc = __builtin_amdgcn_mfma_f32_16x16x32_bf16(a1, pack8(f2, f3), acc, 0, 0, 0);
            int k_out = n0 + lr;
#pragma unroll
            for (int q = 0; q < 4; q++) {
                int m = kg * 4 + q;   // A row
                if (m < KM1)
                    Yb[(size_t)(m * 8 + h) * 512 + k_out] = f2bf(acc[q]);
            }
        }
    }
}

// ---------------------------------------------------------------------------
// Kernel attn: fused scores (MFMA vs Y) + bias MLP + softmax + PV + residual
// + LN.  Block = 16 rows of one batch; 256 threads; grid = 16*64 = 1024
// (4 blocks/CU).  X read from global (L2/L3-hot); V staged in LDS.
// ---------------------------------------------------------------------------
__global__ __launch_bounds__(256) void k_attn(
    const float* __restrict__ X, const float* __restrict__ dist,
    const float* __restrict__ mask,
    const float* __restrict__ Wd1, const float* __restrict__ bd1,
    const float* __restrict__ Wd2, const float* __restrict__ bd2,
    const float* __restrict__ lng, const float* __restrict__ lnb,
    const int* __restrict__ Kp, const int* __restrict__ candIdx,
    const float* __restrict__ candDist,
    const float* __restrict__ Vc, const float* __restrict__ S0,
    const unsigned short* __restrict__ Y,
    float* __restrict__ out) {

    __shared__ float sS[RB][116];              // raw scores (112 cols used)
    __shared__ unsigned short sVc[KM1][520];   // V rows bf16
    __shared__ float sW[RB][8][6];             // softmax weights
    __shared__ float sBias[RB][6][4][8];       // bias MLP partials (4 quarters)
    __shared__ int   snbr[RB][6];
    __shared__ float skd[RB][6];
    __shared__ float srd[RB];
    __shared__ float sE[RB];
    __shared__ float sS0[112];

    int t = threadIdx.x;
    int b = blockIdx.x >> 6, rblk = blockIdx.x & 63;
    int row0 = b * CN + rblk * RB;   // global flat row
    int K = *Kp;

    // ---- phase A: staging (V rows + per-row metadata)
    for (int idx = t; idx < KM1 * 128; idx += 256) {
        int m = idx >> 7, c4 = idx & 127;
        float4 vv = *(const float4*)(Vc + ((size_t)(b * KM1 + m)) * CD + c4 * 4);
        us4 o; o.x = f2bf(vv.x); o.y = f2bf(vv.y); o.z = f2bf(vv.z); o.w = f2bf(vv.w);
        *(us4*)&sVc[m][c4 * 4] = o;
    }
    if (t < 112) sS0[t] = S0[b * 112 + t];
    if (t < RB) {
        int i = rblk * RB + t;
        sE[t]  = mask[b * CN + i];
        srd[t] = dist[b * CN + i];
        int cnt = 0;
        for (int m = 0; m <= K && cnt < K; m++) {
            int c = candIdx[b * KM1 + m];
            if (c != i) { snbr[t][cnt] = m; skd[t][cnt] = candDist[b * KM1 + m]; cnt++; }
        }
    }
    __syncthreads();

    // ---- phase B1: score MFMA  S[r][n] = X_r . Y_n  (K=512), X from global
    {
        int w = t >> 6, lane = t & 63, lr = lane & 15, kg = lane >> 4;
        f32x4 acc0 = {0.f, 0.f, 0.f, 0.f}, acc1 = acc0;
        bool has2 = (w < 3);
        const unsigned short* Yb = Y + (size_t)b * 112 * 512;
        const unsigned short* y0p = Yb + (size_t)(w * 16 + lr) * 512 + kg * 8;
        const unsigned short* y1p = Yb + (size_t)((w + 4) * 16 + lr) * 512 + kg * 8;
        const float* x0 = X + (size_t)(row0 + lr) * CD + kg * 8;
#pragma unroll
        for (int s = 0; s < 16; s++) {
            float4 xa = *(const float4*)(x0 + s * 32);
            float4 xb = *(const float4*)(x0 + s * 32 + 4);
            bf8 a0 = pack8(xa, xb);
            bf8 b0 = *(const bf8*)&y0p[s * 32];
            acc0 = __builtin_amdgcn_mfma_f32_16x16x32_bf16(a0, b0, acc0, 0, 0, 0);
            if (has2) {
                bf8 b1 = *(const bf8*)&y1p[s * 32];
                acc1 = __builtin_amdgcn_mfma_f32_16x16x32_bf16(a0, b1, acc1, 0, 0, 0);
            }
        }
        int n0 = w * 16 + lr;
#pragma unroll
        for (int q = 0; q < 4; q++) sS[kg * 4 + q][n0] = acc0[q];
        if (has2) {
            int n1 = (w + 4) * 16 + lr;
#pragma unroll
            for (int q = 0; q < 4; q++) sS[kg * 4 + q][n1] = acc1[q];
        }
    }
    // ---- phase B2: bias MLP (4 threads per (r,k) pair, quarter hidden each)
    {
        int quarter = t & 3;
        int j0 = quarter * 32;
        for (int pid = t >> 2; pid < RB * K; pid += 64) {
            int r = pid / K, k = pid - r * K;
            float qd = srd[r], kd = skd[r][k];
            float bacc[8];
#pragma unroll
            for (int h = 0; h < 8; h++) bacc[h] = 0.f;
            for (int j = j0; j < j0 + 32; j++) {
                float hid = fmaf(qd, Wd1[j], fmaf(kd, Wd1[128 + j], bd1[j]));
                hid = fmaxf(hid, 0.f);
                float4 wa = *(const float4*)(Wd2 + j * 8);
                float4 wb = *(const float4*)(Wd2 + j * 8 + 4);
                bacc[0] = fmaf(hid, wa.x, bacc[0]);
                bacc[1] = fmaf(hid, wa.y, bacc[1]);
                bacc[2] = fmaf(hid, wa.z, bacc[2]);
                bacc[3] = fmaf(hid, wa.w, bacc[3]);
                bacc[4] = fmaf(hid, wb.x, bacc[4]);
                bacc[5] = fmaf(hid, wb.y, bacc[5]);
                bacc[6] = fmaf(hid, wb.z, bacc[6]);
                bacc[7] = fmaf(hid, wb.w, bacc[7]);
            }
#pragma unroll
            for (int h = 0; h < 8; h++) sBias[r][k][quarter][h] = bacc[h];
        }
    }
    __syncthreads();

    // ---- phase C: blend ego/non-ego scores, multiply bias
    {
        int tot = RB * 8 * K;
        for (int id = t; id < tot; id += 256) {
            int k = id % K; int rh = id / K; int r = rh >> 3, h = rh & 7;
            int m = snbr[r][k];
            float e = sE[r];
            float scq = sS[r][m * 8 + h]      + sS0[m * 8 + h];
            float sce = sS[r][56 + m * 8 + h] + sS0[56 + m * 8 + h];
            float sc = (1.f - e) * scq + e * sce;
            float bias = sBias[r][k][0][h] + sBias[r][k][1][h]
                       + sBias[r][k][2][h] + sBias[r][k][3][h] + bd2[h];
            sW[r][h][k] = sc * 0.125f * bias;
        }
    }
    __syncthreads();

    // ---- phase D: softmax over k (128 tasks)
    if (t < RB * 8) {
        int r = t >> 3, h = t & 7;
        float mx = -3.4e38f;
        for (int k = 0; k < K; k++) mx = fmaxf(mx, sW[r][h][k]);
        float sum = 0.f;
        for (int k = 0; k < K; k++) {
            float w0 = __expf(sW[r][h][k] - mx);
            sW[r][h][k] = w0;
            sum += w0;
        }
        float inv = 1.f / sum;
        for (int k = 0; k < K; k++) sW[r][h][k] *= inv;
    }
    __syncthreads();

    // ---- phase E: PV + residual + LayerNorm (16 threads per row, h = j)
    {
        int r = t >> 4, tr = t & 15;
        const float* xrow = X + (size_t)(row0 + r) * CD;
        float4 vals[8];
        float sum = 0.f, sq = 0.f;
#pragma unroll
        for (int j = 0; j < 8; j++) {
            int d = tr * 4 + j * 64;
            float ax = 0.f, ay = 0.f, az = 0.f, aw = 0.f;
            for (int k = 0; k < K; k++) {
                int m = snbr[r][k];
                float wgt = sW[r][j][k];
                us4 vv = *(const us4*)&sVc[m][d];
                ax = fmaf(wgt, bf2f(vv.x), ax);
                ay = fmaf(wgt, bf2f(vv.y), ay);
                az = fmaf(wgt, bf2f(vv.z), az);
                aw = fmaf(wgt, bf2f(vv.w), aw);
            }
            float4 xv = *(const float4*)(xrow + d);
            float4 v;
            v.x = xv.x + ax; v.y = xv.y + ay; v.z = xv.z + az; v.w = xv.w + aw;
            vals[j] = v;
            sum += v.x + v.y + v.z + v.w;
            sq = fmaf(v.x, v.x, sq); sq = fmaf(v.y, v.y, sq);
            sq = fmaf(v.z, v.z, sq); sq = fmaf(v.w, v.w, sq);
        }
        sum += __shfl_xor(sum, 1, 16); sq += __shfl_xor(sq, 1, 16);
        sum += __shfl_xor(sum, 2, 16); sq += __shfl_xor(sq, 2, 16);
        sum += __shfl_xor(sum, 4, 16); sq += __shfl_xor(sq, 4, 16);
        sum += __shfl_xor(sum, 8, 16); sq += __shfl_xor(sq, 8, 16);
        float mu  = sum * (1.f / 512.f);
        float var = sq * (1.f / 512.f) - mu * mu;
        float inv = rsqrtf(var + 1e-5f);
        float* orow = out + (size_t)(row0 + r) * CD;
#pragma unroll
        for (int j = 0; j < 8; j++) {
            int d = tr * 4 + j * 64;
            float4 g  = *(const float4*)(lng + d);
            float4 bb = *(const float4*)(lnb + d);
            float4 v = vals[j];
            float4 o;
            o.x = (v.x - mu) * inv * g.x + bb.x;
            o.y = (v.y - mu) * inv * g.y + bb.y;
            o.z = (v.z - mu) * inv * g.z + bb.z;
            o.w = (v.w - mu) * inv * g.w + bb.w;
            *(float4*)(orow + d) = o;
        }
    }
}

// ---------------------------------------------------------------------------
extern "C" void kernel_launch(void* const* d_in, const int* in_sizes, int n_in,
                              void* d_out, int out_size, void* d_ws, size_t ws_size,
                              hipStream_t stream) {
    (void)in_sizes; (void)n_in; (void)out_size; (void)ws_size;
    const float* X     = (const float*)d_in[0];
    const float* dist  = (const float*)d_in[1];
    const float* mask  = (const float*)d_in[2];
    const float* speed = (const float*)d_in[3];
    const float* Wq    = (const float*)d_in[4];
    const float* bq    = (const float*)d_in[5];
    const float* Wk    = (const float*)d_in[6];
    const float* bk    = (const float*)d_in[7];
    const float* Wv    = (const float*)d_in[8];
    const float* bv    = (const float*)d_in[9];
    const float* Weq   = (const float*)d_in[10];
    const float* beq   = (const float*)d_in[11];
    const float* Wd1   = (const float*)d_in[16];
    const float* bd1   = (const float*)d_in[17];
    const float* Wd2   = (const float*)d_in[18];
    const float* bd2   = (const float*)d_in[19];
    const float* lng   = (const float*)d_in[20];
    const float* lnb   = (const float*)d_in[21];
    float* out = (float*)d_out;

    char* ws = (char*)d_ws;
    int*   Kp       = (int*)(ws);
    int*   candIdx  = (int*)(ws + 256);
    float* candDist = (float*)(ws + 1024);
    float* S0       = (float*)(ws + 2048);                 // 7168 B
    float* Kc       = (float*)(ws + 16384);                // 229376 B
    float* Vc       = (float*)(ws + 245760);               // 229376 B
    unsigned short* Y   = (unsigned short*)(ws + 475136);  // 1835008 B
    unsigned short* WkT = (unsigned short*)(ws + 2310144); // 524288 B
    unsigned short* WvT = (unsigned short*)(ws + 2834432); // 524288 B

    k_pre<<<145, 256, 0, stream>>>(dist, speed, Wk, Wv, Kp, candIdx, candDist, WkT, WvT);
    k_candkv<<<dim3(CB, 8, 2), 256, 0, stream>>>(X, WkT, bk, WvT, bv, candIdx, Kc, Vc);
    k_Y<<<dim3(CB * 8, 2), 256, 0, stream>>>(Wq, bq, Weq, beq, Kc, S0, Y);
    k_attn<<<CB * (CN / RB), 256, 0, stream>>>(X, dist, mask, Wd1, bd1, Wd2, bd2, lng, lnb,
                                               Kp, candIdx, candDist, Vc, S0, Y, out);
}

// Round 10
// 112.821 us; speedup vs baseline: 2.2772x; 1.2163x over previous
//
#include <hip/hip_runtime.h>
#include <math.h>

constexpr int CB  = 16;
constexpr int CN  = 1024;
constexpr int CD  = 512;
constexpr int KM1 = 7;      // K_MAX + 1 candidate slots per batch
constexpr int RB  = 32;     // rows per k_attn block

typedef __attribute__((ext_vector_type(8))) short bf8;
typedef __attribute__((ext_vector_type(4))) float f32x4;
typedef __attribute__((ext_vector_type(4))) unsigned short us4;

__device__ inline float bf2f(unsigned short u) {
    union { unsigned int i; float f; } v; v.i = ((unsigned)u) << 16; return v.f;
}
__device__ inline unsigned short f2bf(float f) {
    union { unsigned int i; float f; } v; v.f = f;
    unsigned r = v.i + 0x7FFFu + ((v.i >> 16) & 1u);
    return (unsigned short)(r >> 16);
}
// packed f32->bf16 (RNE) via HW instruction: 1 VALU op per 2 elements
__device__ inline unsigned int cvtpk(float lo, float hi) {
    unsigned int r;
    asm("v_cvt_pk_bf16_f32 %0, %1, %2" : "=v"(r) : "v"(lo), "v"(hi));
    return r;
}
__device__ inline bf8 pack8(float4 x, float4 y) {
    union { bf8 v; unsigned int u[4]; } r;
    r.u[0] = cvtpk(x.x, x.y); r.u[1] = cvtpk(x.z, x.w);
    r.u[2] = cvtpk(y.x, y.y); r.u[3] = cvtpk(y.z, y.w);
    return r.v;
}
__device__ inline us4 pack4(float4 x) {
    union { us4 v; unsigned int u[2]; } r;
    r.u[0] = cvtpk(x.x, x.y); r.u[1] = cvtpk(x.z, x.w);
    return r.v;
}

// ---------------------------------------------------------------------------
// Kernel PRE (fused): blocks 0..15 = per-batch top-7; blocks 16..143 =
// transpose Wk/Wv -> bf16 WT[c][k]; block 144 = compute K scalar.
// ---------------------------------------------------------------------------
__global__ __launch_bounds__(256) void k_pre(
    const float* __restrict__ dist, const float* __restrict__ speed,
    const float* __restrict__ Wk, const float* __restrict__ Wv,
    int* __restrict__ Kout,
    int* __restrict__ candIdx, float* __restrict__ candDist,
    unsigned short* __restrict__ WkT, unsigned short* __restrict__ WvT) {
    int t = threadIdx.x;
    int bid = blockIdx.x;

    if (bid < 16) {
        __shared__ float sd[64 * KM1];
        __shared__ int   si[64 * KM1];
        int b = bid;
        if (t < 64) {
            float d7[KM1]; int i7[KM1];
#pragma unroll
            for (int j = 0; j < KM1; j++) { d7[j] = 3.4e38f; i7[j] = -1; }
            for (int i = t; i < CN; i += 64) {
                float d = dist[b * CN + i];
                if (d < d7[KM1 - 1]) {
                    int p = KM1 - 1;
                    while (p > 0 && d7[p - 1] > d) {
                        d7[p] = d7[p - 1]; i7[p] = i7[p - 1]; p--;
                    }
                    d7[p] = d; i7[p] = i;
                }
            }
            for (int j = 0; j < KM1; j++) { sd[t * KM1 + j] = d7[j]; si[t * KM1 + j] = i7[j]; }
        }
        __syncthreads();
        if (t == 0) {
            float m7[KM1]; int mi[KM1];
            for (int j = 0; j < KM1; j++) { m7[j] = 3.4e38f; mi[j] = -1; }
            for (int e = 0; e < 64 * KM1; e++) {
                float d = sd[e];
                if (d < m7[KM1 - 1]) {
                    int ii = si[e];
                    int p = KM1 - 1;
                    while (p > 0 && m7[p - 1] > d) {
                        m7[p] = m7[p - 1]; mi[p] = mi[p - 1]; p--;
                    }
                    m7[p] = d; mi[p] = ii;
                }
            }
            for (int j = 0; j < KM1; j++) {
                candIdx[b * KM1 + j]  = mi[j];
                candDist[b * KM1 + j] = m7[j];
            }
        }
        return;
    }
    if (bid < 144) {
        __shared__ unsigned short tile[64][68];
        int b2 = bid - 16;
        int kt = b2 & 7, ct = (b2 >> 3) & 7, mat = b2 >> 6;
        const float* W = mat ? Wv : Wk;
        unsigned short* WT = mat ? WvT : WkT;
        int k0 = kt * 64, c0 = ct * 64;
#pragma unroll
        for (int p = 0; p < 4; p++) {
            int kr = p * 16 + (t >> 4);
            int cc = (t & 15) * 4;
            float4 v = *(const float4*)(W + (size_t)(k0 + kr) * CD + c0 + cc);
            *(us4*)&tile[kr][cc] = pack4(v);
        }
        __syncthreads();
#pragma unroll
        for (int p = 0; p < 4; p++) {
            int cr = p * 16 + (t >> 4);
            int kk = (t & 15) * 4;
            us4 o;
            o.x = tile[kk + 0][cr];
            o.y = tile[kk + 1][cr];
            o.z = tile[kk + 2][cr];
            o.w = tile[kk + 3][cr];
            *(us4*)(WT + (size_t)(c0 + cr) * CD + k0 + kk) = o;
        }
        return;
    }
    {
        __shared__ int red[256];
        int cnt = 0;
        for (int i = t; i < CB * CN; i += 256) cnt += (dist[i] < 20.0f) ? 1 : 0;
        red[t] = cnt;
        __syncthreads();
        for (int s = 128; s > 0; s >>= 1) {
            if (t < s) red[t] += red[t + s];
            __syncthreads();
        }
        if (t == 0) {
            float ss = 0.f;
            for (int i = 0; i < CB; i++) ss += speed[i];
            int K = 4;
            if (ss / (float)CB > 15.0f) K = (K + 1 > 6) ? 6 : K + 1;
            float density = (float)red[0] / (float)(CB * CN);
            if (density > 0.5f) K = (K + 1 > 6) ? 6 : K + 1;
            if (K > CN - 1) K = CN - 1;
            if (K < 0) K = 0;
            *Kout = K;
        }
    }
}

// ---------------------------------------------------------------------------
// Kernel C (MFMA): K/V projections of the 7 candidate rows per batch.
// ---------------------------------------------------------------------------
__global__ __launch_bounds__(256) void k_candkv(
    const float* __restrict__ X,
    const unsigned short* __restrict__ WkT, const float* __restrict__ bk,
    const unsigned short* __restrict__ WvT, const float* __restrict__ bv,
    const int* __restrict__ candIdx,
    float* __restrict__ Kc, float* __restrict__ Vc) {
    int b   = blockIdx.x;
    int ny  = blockIdx.y;
    int mat = blockIdx.z;
    const unsigned short* WT = mat ? WvT : WkT;
    const float* bias = mat ? bv : bk;
    float*       Out  = mat ? Vc : Kc;

    __shared__ unsigned short sA[16][520];
    int t = threadIdx.x;
    for (int i = t; i < 16 * 128; i += 256) {
        int m = i >> 7, c4 = i & 127;
        float4 xv = {0.f, 0.f, 0.f, 0.f};
        if (m < KM1)
            xv = *(const float4*)(X + (size_t)(b * CN + candIdx[b * KM1 + m]) * CD + c4 * 4);
        *(us4*)&sA[m][c4 * 4] = pack4(xv);
    }
    __syncthreads();

    int w = t >> 6, lane = t & 63, lr = lane & 15, kg = lane >> 4;
    int c = ny * 64 + w * 16 + lr;
    const unsigned short* wtp = WT + (size_t)c * CD + kg * 8;
    f32x4 acc = {0.f, 0.f, 0.f, 0.f};
#pragma unroll
    for (int s = 0; s < 16; s++) {
        bf8 bfr = *(const bf8*)(wtp + s * 32);
        bf8 a   = *(const bf8*)&sA[lr][s * 32 + kg * 8];
        acc = __builtin_amdgcn_mfma_f32_16x16x32_bf16(a, bfr, acc, 0, 0, 0);
    }
    float bv_ = bias[c];
#pragma unroll
    for (int q = 0; q < 4; q++) {
        int m = kg * 4 + q;
        if (m < KM1)
            Out[(size_t)(b * KM1 + m) * CD + c] = acc[q] + bv_;
    }
}

// ---------------------------------------------------------------------------
// Kernel Y (MFMA): per block (b,h,half):
//   Y2[b][k8][n][8]  (interleaved: n = mat*56+m*8+h, k8 = k_out/8)
//   S0[b][mat][m][h] = sum_{c in head} bias[c]*Kc[b][m][c]  (half==0 only)
// ---------------------------------------------------------------------------
__global__ __launch_bounds__(256) void k_Y(
    const float* __restrict__ Wq, const float* __restrict__ bq,
    const float* __restrict__ Weq, const float* __restrict__ beq,
    const float* __restrict__ Kc, float* __restrict__ S0,
    unsigned short* __restrict__ Y) {
    int b = blockIdx.x >> 3, h = blockIdx.x & 7;
    int half = blockIdx.y;
    __shared__ unsigned short sA[16][64];
    __shared__ float sKf[KM1][64];
    int t = threadIdx.x;
    for (int i = t; i < 16 * 64; i += 256) {
        int m = i >> 6, c = i & 63;
        float v = (m < KM1) ? Kc[((size_t)(b * KM1 + m)) * CD + h * 64 + c] : 0.f;
        sA[m][c] = f2bf(v);
        if (m < KM1) sKf[m][c] = v;
    }
    __syncthreads();
    if (half == 0 && t < 14) {
        int mat = t / 7, m = t % 7;
        const float* bias = mat ? beq : bq;
        float s = 0.f;
        for (int c = 0; c < 64; c++) s = fmaf(bias[h * 64 + c], sKf[m][c], s);
        S0[((b * 2 + mat) * KM1 + m) * 8 + h] = s;
    }
    int w = t >> 6, lane = t & 63, lr = lane & 15, kg = lane >> 4;
    bf8 a0 = *(const bf8*)&sA[lr][kg * 8];
    bf8 a1 = *(const bf8*)&sA[lr][32 + kg * 8];
    unsigned short* Y2b = Y + (size_t)b * 64 * 112 * 8;
#pragma unroll
    for (int mat = 0; mat < 2; mat++) {
        const float* W = mat ? Weq : Wq;
#pragma unroll
        for (int nt = 0; nt < 4; nt++) {
            int n0 = (half * 16 + w * 4 + nt) * 16;   // k_out tile base
            const float* wp = W + (size_t)(n0 + lr) * CD + h * 64 + kg * 8;
            float4 f0 = *(const float4*)(wp);
            float4 f1 = *(const float4*)(wp + 4);
            float4 f2 = *(const float4*)(wp + 32);
            float4 f3 = *(const float4*)(wp + 36);
            f32x4 acc = {0.f, 0.f, 0.f, 0.f};
            acc = __builtin_amdgcn_mfma_f32_16x16x32_bf16(a0, pack8(f0, f1), acc, 0, 0, 0);
            acc = __builtin_amdgcn_mfma_f32_16x16x32_bf16(a1, pack8(f2, f3), acc, 0, 0, 0);
            int k_out = n0 + lr;
            int k8 = k_out >> 3, krem = k_out & 7;
#pragma unroll
            for (int q = 0; q < 4; q++) {
                int m = kg * 4 + q;   // A row
                if (m < KM1) {
                    int n = mat * 56 + m * 8 + h;
                    Y2b[((size_t)k8 * 112 + n) * 8 + krem] = f2bf(acc[q]);
                }
            }
        }
    }
}

// ---------------------------------------------------------------------------
// Kernel attn: fused scores (MFMA vs Y2) + bias MLP + softmax + PV + residual
// + LN.  Block = 32 rows of one batch; 256 threads; grid = 16*32 = 512.
// X read from global; V staged in LDS; Y2 interleaved -> coalesced B-frags.
// ---------------------------------------------------------------------------
__global__ __launch_bounds__(256) void k_attn(
    const float* __restrict__ X, const float* __restrict__ dist,
    const float* __restrict__ mask,
    const float* __restrict__ Wd1, const float* __restrict__ bd1,
    const float* __restrict__ Wd2, const float* __restrict__ bd2,
    const float* __restrict__ lng, const float* __restrict__ lnb,
    const int* __restrict__ Kp, const int* __restrict__ candIdx,
    const float* __restrict__ candDist,
    const float* __restrict__ Vc, const float* __restrict__ S0,
    const unsigned short* __restrict__ Y,
    float* __restrict__ out) {

    __shared__ float sS[RB][116];              // raw scores (112 cols used)
    __shared__ unsigned short sVc[KM1][520];   // V rows bf16
    __shared__ float sW[RB][8][6];             // softmax weights
    __shared__ float sBias[RB][6][2][8];       // bias MLP partials (2 halves)
    __shared__ int   snbr[RB][6];
    __shared__ float skd[RB][6];
    __shared__ float srd[RB];
    __shared__ float sE[RB];
    __shared__ float sS0[112];

    int t = threadIdx.x;
    int b = blockIdx.x >> 5, rblk = blockIdx.x & 31;
    int row0 = b * CN + rblk * RB;   // global flat row
    int K = *Kp;

    // ---- phase A: staging (V rows + per-row metadata only)
    for (int idx = t; idx < KM1 * 128; idx += 256) {
        int m = idx >> 7, c4 = idx & 127;
        float4 vv = *(const float4*)(Vc + ((size_t)(b * KM1 + m)) * CD + c4 * 4);
        *(us4*)&sVc[m][c4 * 4] = pack4(vv);
    }
    if (t < 112) sS0[t] = S0[b * 112 + t];
    if (t < RB) {
        int i = rblk * RB + t;
        sE[t]  = mask[b * CN + i];
        srd[t] = dist[b * CN + i];
        int cnt = 0;
        for (int m = 0; m <= K && cnt < K; m++) {
            int c = candIdx[b * KM1 + m];
            if (c != i) { snbr[t][cnt] = m; skd[t][cnt] = candDist[b * KM1 + m]; cnt++; }
        }
    }
    __syncthreads();

    // ---- phase B1: score MFMA  S[r][n] = X_r . Y_n  (K=512), X global, Y2
    {
        int w = t >> 6, lane = t & 63, lr = lane & 15, kg = lane >> 4;
        f32x4 acc00 = {0.f, 0.f, 0.f, 0.f}, acc10 = acc00, acc01 = acc00, acc11 = acc00;
        bool has2 = (w < 3);
        // Y2 layout: [b][k8][n][8]; per-lane base at (kg, n=w*16+lr)
        const unsigned short* ypk = Y + ((size_t)b * 64 * 112 + (size_t)kg * 112 + (w * 16 + lr)) * 8;
        const float* x0 = X + (size_t)(row0 + lr) * CD + kg * 8;
        const float* x1 = X + (size_t)(row0 + 16 + lr) * CD + kg * 8;
#pragma unroll
        for (int s = 0; s < 16; s++) {
            int k0 = s * 32;
            float4 xa0 = *(const float4*)(x0 + k0);
            float4 xb0 = *(const float4*)(x0 + k0 + 4);
            float4 xa1 = *(const float4*)(x1 + k0);
            float4 xb1 = *(const float4*)(x1 + k0 + 4);
            bf8 a0 = pack8(xa0, xb0);
            bf8 a1 = pack8(xa1, xb1);
            const unsigned short* ys = ypk + (size_t)s * 4 * 112 * 8;
            bf8 b0 = *(const bf8*)ys;
            acc00 = __builtin_amdgcn_mfma_f32_16x16x32_bf16(a0, b0, acc00, 0, 0, 0);
            acc10 = __builtin_amdgcn_mfma_f32_16x16x32_bf16(a1, b0, acc10, 0, 0, 0);
            if (has2) {
                bf8 b1 = *(const bf8*)(ys + 512);   // n offset +64 -> +64*8 shorts
                acc01 = __builtin_amdgcn_mfma_f32_16x16x32_bf16(a0, b1, acc01, 0, 0, 0);
                acc11 = __builtin_amdgcn_mfma_f32_16x16x32_bf16(a1, b1, acc11, 0, 0, 0);
            }
        }
        int n0 = w * 16 + lr;
#pragma unroll
        for (int q = 0; q < 4; q++) {
            sS[kg * 4 + q][n0]      = acc00[q];
            sS[16 + kg * 4 + q][n0] = acc10[q];
        }
        if (has2) {
            int n1 = (w + 4) * 16 + lr;
#pragma unroll
            for (int q = 0; q < 4; q++) {
                sS[kg * 4 + q][n1]      = acc01[q];
                sS[16 + kg * 4 + q][n1] = acc11[q];
            }
        }
    }
    // ---- phase B2: bias MLP (2 threads per (r,k) pair, split hidden dim)
    {
        int half = t & 1;
        int j0 = half * 64;
        for (int pid = t >> 1; pid < RB * K; pid += 128) {
            int r = pid / K, k = pid - r * K;
            float qd = srd[r], kd = skd[r][k];
            float bacc[8];
#pragma unroll
            for (int h = 0; h < 8; h++) bacc[h] = 0.f;
            for (int j = j0; j < j0 + 64; j++) {
                float hid = fmaf(qd, Wd1[j], fmaf(kd, Wd1[128 + j], bd1[j]));
                hid = fmaxf(hid, 0.f);
                float4 wa = *(const float4*)(Wd2 + j * 8);
                float4 wb = *(const float4*)(Wd2 + j * 8 + 4);
                bacc[0] = fmaf(hid, wa.x, bacc[0]);
                bacc[1] = fmaf(hid, wa.y, bacc[1]);
                bacc[2] = fmaf(hid, wa.z, bacc[2]);
                bacc[3] = fmaf(hid, wa.w, bacc[3]);
                bacc[4] = fmaf(hid, wb.x, bacc[4]);
                bacc[5] = fmaf(hid, wb.y, bacc[5]);
                bacc[6] = fmaf(hid, wb.z, bacc[6]);
                bacc[7] = fmaf(hid, wb.w, bacc[7]);
            }
#pragma unroll
            for (int h = 0; h < 8; h++) sBias[r][k][half][h] = bacc[h];
        }
    }
    __syncthreads();

    // ---- phase C: blend ego/non-ego scores, multiply bias
    {
        int tot = RB * 8 * K;
        for (int id = t; id < tot; id += 256) {
            int k = id % K; int rh = id / K; int r = rh >> 3, h = rh & 7;
            int m = snbr[r][k];
            float e = sE[r];
            float scq = sS[r][m * 8 + h]      + sS0[m * 8 + h];
            float sce = sS[r][56 + m * 8 + h] + sS0[56 + m * 8 + h];
            float sc = (1.f - e) * scq + e * sce;
            float bias = sBias[r][k][0][h] + sBias[r][k][1][h] + bd2[h];
            sW[r][h][k] = sc * 0.125f * bias;
        }
    }
    __syncthreads();

    // ---- phase D: softmax over k (256 tasks exactly)
    {
        int r = t >> 3, h = t & 7;
        float mx = -3.4e38f;
        for (int k = 0; k < K; k++) mx = fmaxf(mx, sW[r][h][k]);
        float sum = 0.f;
        for (int k = 0; k < K; k++) {
            float w0 = __expf(sW[r][h][k] - mx);
            sW[r][h][k] = w0;
            sum += w0;
        }
        float inv = 1.f / sum;
        for (int k = 0; k < K; k++) sW[r][h][k] *= inv;
    }
    __syncthreads();

    // ---- phase E: PV + residual + LayerNorm (8 threads per row)
    {
        int r = t >> 3, tr = t & 7;
        const float* xrow = X + (size_t)(row0 + r) * CD;
        float4 vals[16];
        float sum = 0.f, sq = 0.f;
#pragma unroll
        for (int j = 0; j < 16; j++) {
            int d = tr * 4 + j * 32;
            int h = j >> 1;
            float ax = 0.f, ay = 0.f, az = 0.f, aw = 0.f;
            for (int k = 0; k < K; k++) {
                int m = snbr[r][k];
                float wgt = sW[r][h][k];
                us4 vv = *(const us4*)&sVc[m][d];
                ax = fmaf(wgt, bf2f(vv.x), ax);
                ay = fmaf(wgt, bf2f(vv.y), ay);
                az = fmaf(wgt, bf2f(vv.z), az);
                aw = fmaf(wgt, bf2f(vv.w), aw);
            }
            float4 xv = *(const float4*)(xrow + d);
            float4 v;
            v.x = xv.x + ax; v.y = xv.y + ay; v.z = xv.z + az; v.w = xv.w + aw;
            vals[j] = v;
            sum += v.x + v.y + v.z + v.w;
            sq = fmaf(v.x, v.x, sq); sq = fmaf(v.y, v.y, sq);
            sq = fmaf(v.z, v.z, sq); sq = fmaf(v.w, v.w, sq);
        }
        sum += __shfl_xor(sum, 1); sq += __shfl_xor(sq, 1);
        sum += __shfl_xor(sum, 2); sq += __shfl_xor(sq, 2);
        sum += __shfl_xor(sum, 4); sq += __shfl_xor(sq, 4);
        float mu  = sum * (1.f / 512.f);
        float var = sq * (1.f / 512.f) - mu * mu;
        float inv = rsqrtf(var + 1e-5f);
        float* orow = out + (size_t)(row0 + r) * CD;
#pragma unroll
        for (int j = 0; j < 16; j++) {
            int d = tr * 4 + j * 32;
            float4 g  = *(const float4*)(lng + d);
            float4 bb = *(const float4*)(lnb + d);
            float4 v = vals[j];
            float4 o;
            o.x = (v.x - mu) * inv * g.x + bb.x;
            o.y = (v.y - mu) * inv * g.y + bb.y;
            o.z = (v.z - mu) * inv * g.z + bb.z;
            o.w = (v.w - mu) * inv * g.w + bb.w;
            *(float4*)(orow + d) = o;
        }
    }
}

// ---------------------------------------------------------------------------
extern "C" void kernel_launch(void* const* d_in, const int* in_sizes, int n_in,
                              void* d_out, int out_size, void* d_ws, size_t ws_size,
                              hipStream_t stream) {
    (void)in_sizes; (void)n_in; (void)out_size; (void)ws_size;
    const float* X     = (const float*)d_in[0];
    const float* dist  = (const float*)d_in[1];
    const float* mask  = (const float*)d_in[2];
    const float* speed = (const float*)d_in[3];
    const float* Wq    = (const float*)d_in[4];
    const float* bq    = (const float*)d_in[5];
    const float* Wk    = (const float*)d_in[6];
    const float* bk    = (const float*)d_in[7];
    const float* Wv    = (const float*)d_in[8];
    const float* bv    = (const float*)d_in[9];
    const float* Weq   = (const float*)d_in[10];
    const float* beq   = (const float*)d_in[11];
    const float* Wd1   = (const float*)d_in[16];
    const float* bd1   = (const float*)d_in[17];
    const float* Wd2   = (const float*)d_in[18];
    const float* bd2   = (const float*)d_in[19];
    const float* lng   = (const float*)d_in[20];
    const float* lnb   = (const float*)d_in[21];
    float* out = (float*)d_out;

    char* ws = (char*)d_ws;
    int*   Kp       = (int*)(ws);
    int*   candIdx  = (int*)(ws + 256);
    float* candDist = (float*)(ws + 1024);
    float* S0       = (float*)(ws + 2048);                 // 7168 B
    float* Kc       = (float*)(ws + 16384);                // 229376 B
    float* Vc       = (float*)(ws + 245760);               // 229376 B
    unsigned short* Y   = (unsigned short*)(ws + 475136);  // 1835008 B (Y2 layout)
    unsigned short* WkT = (unsigned short*)(ws + 2310144); // 524288 B
    unsigned short* WvT = (unsigned short*)(ws + 2834432); // 524288 B

    k_pre<<<145, 256, 0, stream>>>(dist, speed, Wk, Wv, Kp, candIdx, candDist, WkT, WvT);
    k_candkv<<<dim3(CB, 8, 2), 256, 0, stream>>>(X, WkT, bk, WvT, bv, candIdx, Kc, Vc);
    k_Y<<<dim3(CB * 8, 2), 256, 0, stream>>>(Wq, bq, Weq, beq, Kc, S0, Y);
    k_attn<<<CB * (CN / RB), 256, 0, stream>>>(X, dist, mask, Wd1, bd1, Wd2, bd2, lng, lnb,
                                               Kp, candIdx, candDist, Vc, S0, Y, out);
}

// Round 11
// 110.556 us; speedup vs baseline: 2.3238x; 1.0205x over previous
//
#include <hip/hip_runtime.h>
#include <math.h>

constexpr int CB  = 16;
constexpr int CN  = 1024;
constexpr int CD  = 512;
constexpr int KM1 = 7;      // K_MAX + 1 candidate slots per batch
constexpr int RB  = 32;     // rows per k_attn block

typedef __attribute__((ext_vector_type(8))) short bf8;
typedef __attribute__((ext_vector_type(4))) float f32x4;
typedef __attribute__((ext_vector_type(4))) unsigned short us4;

__device__ inline float bf2f(unsigned short u) {
    union { unsigned int i; float f; } v; v.i = ((unsigned)u) << 16; return v.f;
}
__device__ inline unsigned short f2bf(float f) {
    union { unsigned int i; float f; } v; v.f = f;
    unsigned r = v.i + 0x7FFFu + ((v.i >> 16) & 1u);
    return (unsigned short)(r >> 16);
}
// packed f32->bf16 (RNE) via HW instruction: 1 VALU op per 2 elements
__device__ inline unsigned int cvtpk(float lo, float hi) {
    unsigned int r;
    asm("v_cvt_pk_bf16_f32 %0, %1, %2" : "=v"(r) : "v"(lo), "v"(hi));
    return r;
}
__device__ inline bf8 pack8(float4 x, float4 y) {
    union { bf8 v; unsigned int u[4]; } r;
    r.u[0] = cvtpk(x.x, x.y); r.u[1] = cvtpk(x.z, x.w);
    r.u[2] = cvtpk(y.x, y.y); r.u[3] = cvtpk(y.z, y.w);
    return r.v;
}
__device__ inline us4 pack4(float4 x) {
    union { us4 v; unsigned int u[2]; } r;
    r.u[0] = cvtpk(x.x, x.y); r.u[1] = cvtpk(x.z, x.w);
    return r.v;
}

// ---------------------------------------------------------------------------
// Kernel PRE (fused): blocks 0..15 = per-batch top-7; blocks 16..143 =
// transpose Wk/Wv -> bf16 WT[c][k]; block 144 = compute K scalar.
// ---------------------------------------------------------------------------
__global__ __launch_bounds__(256) void k_pre(
    const float* __restrict__ dist, const float* __restrict__ speed,
    const float* __restrict__ Wk, const float* __restrict__ Wv,
    int* __restrict__ Kout,
    int* __restrict__ candIdx, float* __restrict__ candDist,
    unsigned short* __restrict__ WkT, unsigned short* __restrict__ WvT) {
    int t = threadIdx.x;
    int bid = blockIdx.x;

    if (bid < 16) {
        __shared__ float sd[64 * KM1];
        __shared__ int   si[64 * KM1];
        int b = bid;
        if (t < 64) {
            float d7[KM1]; int i7[KM1];
#pragma unroll
            for (int j = 0; j < KM1; j++) { d7[j] = 3.4e38f; i7[j] = -1; }
            for (int i = t; i < CN; i += 64) {
                float d = dist[b * CN + i];
                if (d < d7[KM1 - 1]) {
                    int p = KM1 - 1;
                    while (p > 0 && d7[p - 1] > d) {
                        d7[p] = d7[p - 1]; i7[p] = i7[p - 1]; p--;
                    }
                    d7[p] = d; i7[p] = i;
                }
            }
            for (int j = 0; j < KM1; j++) { sd[t * KM1 + j] = d7[j]; si[t * KM1 + j] = i7[j]; }
        }
        __syncthreads();
        if (t == 0) {
            float m7[KM1]; int mi[KM1];
            for (int j = 0; j < KM1; j++) { m7[j] = 3.4e38f; mi[j] = -1; }
            for (int e = 0; e < 64 * KM1; e++) {
                float d = sd[e];
                if (d < m7[KM1 - 1]) {
                    int ii = si[e];
                    int p = KM1 - 1;
                    while (p > 0 && m7[p - 1] > d) {
                        m7[p] = m7[p - 1]; mi[p] = mi[p - 1]; p--;
                    }
                    m7[p] = d; mi[p] = ii;
                }
            }
            for (int j = 0; j < KM1; j++) {
                candIdx[b * KM1 + j]  = mi[j];
                candDist[b * KM1 + j] = m7[j];
            }
        }
        return;
    }
    if (bid < 144) {
        __shared__ unsigned short tile[64][68];
        int b2 = bid - 16;
        int kt = b2 & 7, ct = (b2 >> 3) & 7, mat = b2 >> 6;
        const float* W = mat ? Wv : Wk;
        unsigned short* WT = mat ? WvT : WkT;
        int k0 = kt * 64, c0 = ct * 64;
#pragma unroll
        for (int p = 0; p < 4; p++) {
            int kr = p * 16 + (t >> 4);
            int cc = (t & 15) * 4;
            float4 v = *(const float4*)(W + (size_t)(k0 + kr) * CD + c0 + cc);
            *(us4*)&tile[kr][cc] = pack4(v);
        }
        __syncthreads();
#pragma unroll
        for (int p = 0; p < 4; p++) {
            int cr = p * 16 + (t >> 4);
            int kk = (t & 15) * 4;
            us4 o;
            o.x = tile[kk + 0][cr];
            o.y = tile[kk + 1][cr];
            o.z = tile[kk + 2][cr];
            o.w = tile[kk + 3][cr];
            *(us4*)(WT + (size_t)(c0 + cr) * CD + k0 + kk) = o;
        }
        return;
    }
    {
        __shared__ int red[256];
        int cnt = 0;
        for (int i = t; i < CB * CN; i += 256) cnt += (dist[i] < 20.0f) ? 1 : 0;
        red[t] = cnt;
        __syncthreads();
        for (int s = 128; s > 0; s >>= 1) {
            if (t < s) red[t] += red[t + s];
            __syncthreads();
        }
        if (t == 0) {
            float ss = 0.f;
            for (int i = 0; i < CB; i++) ss += speed[i];
            int K = 4;
            if (ss / (float)CB > 15.0f) K = (K + 1 > 6) ? 6 : K + 1;
            float density = (float)red[0] / (float)(CB * CN);
            if (density > 0.5f) K = (K + 1 > 6) ? 6 : K + 1;
            if (K > CN - 1) K = CN - 1;
            if (K < 0) K = 0;
            *Kout = K;
        }
    }
}

// ---------------------------------------------------------------------------
// Kernel C (MFMA): K/V projections of the 7 candidate rows per batch.
// ---------------------------------------------------------------------------
__global__ __launch_bounds__(256) void k_candkv(
    const float* __restrict__ X,
    const unsigned short* __restrict__ WkT, const float* __restrict__ bk,
    const unsigned short* __restrict__ WvT, const float* __restrict__ bv,
    const int* __restrict__ candIdx,
    float* __restrict__ Kc, float* __restrict__ Vc) {
    int b   = blockIdx.x;
    int ny  = blockIdx.y;
    int mat = blockIdx.z;
    const unsigned short* WT = mat ? WvT : WkT;
    const float* bias = mat ? bv : bk;
    float*       Out  = mat ? Vc : Kc;

    __shared__ unsigned short sA[16][520];
    int t = threadIdx.x;
    for (int i = t; i < 16 * 128; i += 256) {
        int m = i >> 7, c4 = i & 127;
        float4 xv = {0.f, 0.f, 0.f, 0.f};
        if (m < KM1)
            xv = *(const float4*)(X + (size_t)(b * CN + candIdx[b * KM1 + m]) * CD + c4 * 4);
        *(us4*)&sA[m][c4 * 4] = pack4(xv);
    }
    __syncthreads();

    int w = t >> 6, lane = t & 63, lr = lane & 15, kg = lane >> 4;
    int c = ny * 64 + w * 16 + lr;
    const unsigned short* wtp = WT + (size_t)c * CD + kg * 8;
    f32x4 acc = {0.f, 0.f, 0.f, 0.f};
#pragma unroll
    for (int s = 0; s < 16; s++) {
        bf8 bfr = *(const bf8*)(wtp + s * 32);
        bf8 a   = *(const bf8*)&sA[lr][s * 32 + kg * 8];
        acc = __builtin_amdgcn_mfma_f32_16x16x32_bf16(a, bfr, acc, 0, 0, 0);
    }
    float bv_ = bias[c];
#pragma unroll
    for (int q = 0; q < 4; q++) {
        int m = kg * 4 + q;
        if (m < KM1)
            Out[(size_t)(b * KM1 + m) * CD + c] = acc[q] + bv_;
    }
}

// ---------------------------------------------------------------------------
// Kernel Y (MFMA): per block (b,h,half):
//   Y2[b][k8][n][8]  (interleaved: n = mat*56+m*8+h, k8 = k_out/8)
//   S0[b][mat][m][h] = sum_{c in head} bias[c]*Kc[b][m][c]  (half==0 only)
// ---------------------------------------------------------------------------
__global__ __launch_bounds__(256) void k_Y(
    const float* __restrict__ Wq, const float* __restrict__ bq,
    const float* __restrict__ Weq, const float* __restrict__ beq,
    const float* __restrict__ Kc, float* __restrict__ S0,
    unsigned short* __restrict__ Y) {
    int b = blockIdx.x >> 3, h = blockIdx.x & 7;
    int half = blockIdx.y;
    __shared__ unsigned short sA[16][64];
    __shared__ float sKf[KM1][64];
    int t = threadIdx.x;
    for (int i = t; i < 16 * 64; i += 256) {
        int m = i >> 6, c = i & 63;
        float v = (m < KM1) ? Kc[((size_t)(b * KM1 + m)) * CD + h * 64 + c] : 0.f;
        sA[m][c] = f2bf(v);
        if (m < KM1) sKf[m][c] = v;
    }
    __syncthreads();
    if (half == 0 && t < 14) {
        int mat = t / 7, m = t % 7;
        const float* bias = mat ? beq : bq;
        float s = 0.f;
        for (int c = 0; c < 64; c++) s = fmaf(bias[h * 64 + c], sKf[m][c], s);
        S0[((b * 2 + mat) * KM1 + m) * 8 + h] = s;
    }
    int w = t >> 6, lane = t & 63, lr = lane & 15, kg = lane >> 4;
    bf8 a0 = *(const bf8*)&sA[lr][kg * 8];
    bf8 a1 = *(const bf8*)&sA[lr][32 + kg * 8];
    unsigned short* Y2b = Y + (size_t)b * 64 * 112 * 8;
#pragma unroll
    for (int mat = 0; mat < 2; mat++) {
        const float* W = mat ? Weq : Wq;
#pragma unroll
        for (int nt = 0; nt < 4; nt++) {
            int n0 = (half * 16 + w * 4 + nt) * 16;   // k_out tile base
            const float* wp = W + (size_t)(n0 + lr) * CD + h * 64 + kg * 8;
            float4 f0 = *(const float4*)(wp);
            float4 f1 = *(const float4*)(wp + 4);
            float4 f2 = *(const float4*)(wp + 32);
            float4 f3 = *(const float4*)(wp + 36);
            f32x4 acc = {0.f, 0.f, 0.f, 0.f};
            acc = __builtin_amdgcn_mfma_f32_16x16x32_bf16(a0, pack8(f0, f1), acc, 0, 0, 0);
            acc = __builtin_amdgcn_mfma_f32_16x16x32_bf16(a1, pack8(f2, f3), acc, 0, 0, 0);
            int k_out = n0 + lr;
            int k8 = k_out >> 3, krem = k_out & 7;
#pragma unroll
            for (int q = 0; q < 4; q++) {
                int m = kg * 4 + q;   // A row
                if (m < KM1) {
                    int n = mat * 56 + m * 8 + h;
                    Y2b[((size_t)k8 * 112 + n) * 8 + krem] = f2bf(acc[q]);
                }
            }
        }
    }
}

// ---------------------------------------------------------------------------
// Kernel attn: 512 threads/block, 32 rows/block, grid 512 (16 waves/CU).
//   Waves 0-3: score MFMA (B1).  Waves 4-7: bias MLP (B2) -- concurrent.
//   Then blend+softmax+W7-aggregate, and PV via fixed-7 slot loop + LN.
// ---------------------------------------------------------------------------
__global__ __launch_bounds__(512) void k_attn(
    const float* __restrict__ X, const float* __restrict__ dist,
    const float* __restrict__ mask,
    const float* __restrict__ Wd1, const float* __restrict__ bd1,
    const float* __restrict__ Wd2, const float* __restrict__ bd2,
    const float* __restrict__ lng, const float* __restrict__ lnb,
    const int* __restrict__ Kp, const int* __restrict__ candIdx,
    const float* __restrict__ candDist,
    const float* __restrict__ Vc, const float* __restrict__ S0,
    const unsigned short* __restrict__ Y,
    float* __restrict__ out) {

    __shared__ float sS[RB][116];              // raw scores (112 cols used)
    __shared__ unsigned short sVc[KM1][520];   // V rows bf16
    __shared__ float sW[RB][8][6];             // softmax weights
    __shared__ float sW7[RB][8][8];            // aggregated slot weights
    __shared__ float sBias[RB][6][2][8];       // bias MLP partials (2 halves)
    __shared__ int   snbr[RB][6];
    __shared__ float skd[RB][6];
    __shared__ float srd[RB];
    __shared__ float sE[RB];
    __shared__ float sS0[112];

    int t = threadIdx.x;
    int b = blockIdx.x >> 5, rblk = blockIdx.x & 31;
    int row0 = b * CN + rblk * RB;   // global flat row
    int K = *Kp;

    // ---- phase A: staging (V rows + per-row metadata only)
    for (int idx = t; idx < KM1 * 128; idx += 512) {
        int m = idx >> 7, c4 = idx & 127;
        float4 vv = *(const float4*)(Vc + ((size_t)(b * KM1 + m)) * CD + c4 * 4);
        *(us4*)&sVc[m][c4 * 4] = pack4(vv);
    }
    if (t < 112) sS0[t] = S0[b * 112 + t];
    if (t < RB) {
        int i = rblk * RB + t;
        sE[t]  = mask[b * CN + i];
        srd[t] = dist[b * CN + i];
        int cnt = 0;
        for (int m = 0; m <= K && cnt < K; m++) {
            int c = candIdx[b * KM1 + m];
            if (c != i) { snbr[t][cnt] = m; skd[t][cnt] = candDist[b * KM1 + m]; cnt++; }
        }
    }
    __syncthreads();

    int w = t >> 6;
    if (w < 4) {
        // ---- phase B1 (waves 0-3): score MFMA  S[r][n] = X_r . Y_n
        int lane = t & 63, lr = lane & 15, kg = lane >> 4;
        f32x4 acc00 = {0.f, 0.f, 0.f, 0.f}, acc10 = acc00, acc01 = acc00, acc11 = acc00;
        bool has2 = (w < 3);
        // Y2 layout: [b][k8][n][8]; per-lane base at (kg, n=w*16+lr)
        const unsigned short* ypk = Y + ((size_t)b * 64 * 112 + (size_t)kg * 112 + (w * 16 + lr)) * 8;
        const float* x0 = X + (size_t)(row0 + lr) * CD + kg * 8;
        const float* x1 = X + (size_t)(row0 + 16 + lr) * CD + kg * 8;
#pragma unroll
        for (int s = 0; s < 16; s++) {
            int k0 = s * 32;
            float4 xa0 = *(const float4*)(x0 + k0);
            float4 xb0 = *(const float4*)(x0 + k0 + 4);
            float4 xa1 = *(const float4*)(x1 + k0);
            float4 xb1 = *(const float4*)(x1 + k0 + 4);
            bf8 a0 = pack8(xa0, xb0);
            bf8 a1 = pack8(xa1, xb1);
            const unsigned short* ys = ypk + (size_t)s * 4 * 112 * 8;
            bf8 b0 = *(const bf8*)ys;
            acc00 = __builtin_amdgcn_mfma_f32_16x16x32_bf16(a0, b0, acc00, 0, 0, 0);
            acc10 = __builtin_amdgcn_mfma_f32_16x16x32_bf16(a1, b0, acc10, 0, 0, 0);
            if (has2) {
                bf8 b1 = *(const bf8*)(ys + 512);   // n offset +64 -> +64*8 shorts
                acc01 = __builtin_amdgcn_mfma_f32_16x16x32_bf16(a0, b1, acc01, 0, 0, 0);
                acc11 = __builtin_amdgcn_mfma_f32_16x16x32_bf16(a1, b1, acc11, 0, 0, 0);
            }
        }
        int n0 = w * 16 + lr;
#pragma unroll
        for (int q = 0; q < 4; q++) {
            sS[kg * 4 + q][n0]      = acc00[q];
            sS[16 + kg * 4 + q][n0] = acc10[q];
        }
        if (has2) {
            int n1 = (w + 4) * 16 + lr;
#pragma unroll
            for (int q = 0; q < 4; q++) {
                sS[kg * 4 + q][n1]      = acc01[q];
                sS[16 + kg * 4 + q][n1] = acc11[q];
            }
        }
    } else {
        // ---- phase B2 (waves 4-7): bias MLP, 2 tasks (halves) per (r,k)
        int tot2 = RB * K * 2;
        for (int task = t - 256; task < tot2; task += 256) {
            int half = task & 1;
            int pid = task >> 1;
            int r = pid / K, k = pid - r * K;
            int j0 = half * 64;
            float qd = srd[r], kd = skd[r][k];
            float bacc[8];
#pragma unroll
            for (int h = 0; h < 8; h++) bacc[h] = 0.f;
            for (int j = j0; j < j0 + 64; j++) {
                float hid = fmaf(qd, Wd1[j], fmaf(kd, Wd1[128 + j], bd1[j]));
                hid = fmaxf(hid, 0.f);
                float4 wa = *(const float4*)(Wd2 + j * 8);
                float4 wb = *(const float4*)(Wd2 + j * 8 + 4);
                bacc[0] = fmaf(hid, wa.x, bacc[0]);
                bacc[1] = fmaf(hid, wa.y, bacc[1]);
                bacc[2] = fmaf(hid, wa.z, bacc[2]);
                bacc[3] = fmaf(hid, wa.w, bacc[3]);
                bacc[4] = fmaf(hid, wb.x, bacc[4]);
                bacc[5] = fmaf(hid, wb.y, bacc[5]);
                bacc[6] = fmaf(hid, wb.z, bacc[6]);
                bacc[7] = fmaf(hid, wb.w, bacc[7]);
            }
#pragma unroll
            for (int h = 0; h < 8; h++) sBias[r][k][half][h] = bacc[h];
        }
    }
    __syncthreads();

    // ---- phase C: blend ego/non-ego scores, multiply bias
    {
        int tot = RB * 8 * K;
        for (int id = t; id < tot; id += 512) {
            int k = id % K; int rh = id / K; int r = rh >> 3, h = rh & 7;
            int m = snbr[r][k];
            float e = sE[r];
            float scq = sS[r][m * 8 + h]      + sS0[m * 8 + h];
            float sce = sS[r][56 + m * 8 + h] + sS0[56 + m * 8 + h];
            float sc = (1.f - e) * scq + e * sce;
            float bias = sBias[r][k][0][h] + sBias[r][k][1][h] + bd2[h];
            sW[r][h][k] = sc * 0.125f * bias;
        }
    }
    __syncthreads();

    // ---- phase D: softmax over k + W7 slot aggregation (256 tasks)
    if (t < RB * 8) {
        int r = t >> 3, h = t & 7;
        float mx = -3.4e38f;
        for (int k = 0; k < K; k++) mx = fmaxf(mx, sW[r][h][k]);
        float sum = 0.f;
        for (int k = 0; k < K; k++) {
            float w0 = __expf(sW[r][h][k] - mx);
            sW[r][h][k] = w0;
            sum += w0;
        }
        float inv = 1.f / sum;
        float w7[KM1];
#pragma unroll
        for (int m = 0; m < KM1; m++) w7[m] = 0.f;
        for (int k = 0; k < K; k++) w7[snbr[r][k]] += sW[r][h][k] * inv;
#pragma unroll
        for (int m = 0; m < KM1; m++) sW7[r][h][m] = w7[m];
    }
    __syncthreads();

    // ---- phase E: PV (fixed 7-slot loop) + residual + LN (16 thr/row, h=j)
    {
        int r = t >> 4, tr = t & 15;
        const float* xrow = X + (size_t)(row0 + r) * CD;
        float4 vals[8];
        float sum = 0.f, sq = 0.f;
#pragma unroll
        for (int j = 0; j < 8; j++) {
            int d = tr * 4 + j * 64;    // head h = j
            float ax = 0.f, ay = 0.f, az = 0.f, aw = 0.f;
#pragma unroll
            for (int m = 0; m < KM1; m++) {
                float wgt = sW7[r][j][m];
                us4 vv = *(const us4*)&sVc[m][d];
                ax = fmaf(wgt, bf2f(vv.x), ax);
                ay = fmaf(wgt, bf2f(vv.y), ay);
                az = fmaf(wgt, bf2f(vv.z), az);
                aw = fmaf(wgt, bf2f(vv.w), aw);
            }
            float4 xv = *(const float4*)(xrow + d);
            float4 v;
            v.x = xv.x + ax; v.y = xv.y + ay; v.z = xv.z + az; v.w = xv.w + aw;
            vals[j] = v;
            sum += v.x + v.y + v.z + v.w;
            sq = fmaf(v.x, v.x, sq); sq = fmaf(v.y, v.y, sq);
            sq = fmaf(v.z, v.z, sq); sq = fmaf(v.w, v.w, sq);
        }
        sum += __shfl_xor(sum, 1, 16); sq += __shfl_xor(sq, 1, 16);
        sum += __shfl_xor(sum, 2, 16); sq += __shfl_xor(sq, 2, 16);
        sum += __shfl_xor(sum, 4, 16); sq += __shfl_xor(sq, 4, 16);
        sum += __shfl_xor(sum, 8, 16); sq += __shfl_xor(sq, 8, 16);
        float mu  = sum * (1.f / 512.f);
        float var = sq * (1.f / 512.f) - mu * mu;
        float inv = rsqrtf(var + 1e-5f);
        float* orow = out + (size_t)(row0 + r) * CD;
#pragma unroll
        for (int j = 0; j < 8; j++) {
            int d = tr * 4 + j * 64;
            float4 g  = *(const float4*)(lng + d);
            float4 bb = *(const float4*)(lnb + d);
            float4 v = vals[j];
            float4 o;
            o.x = (v.x - mu) * inv * g.x + bb.x;
            o.y = (v.y - mu) * inv * g.y + bb.y;
            o.z = (v.z - mu) * inv * g.z + bb.z;
            o.w = (v.w - mu) * inv * g.w + bb.w;
            *(float4*)(orow + d) = o;
        }
    }
}

// ---------------------------------------------------------------------------
extern "C" void kernel_launch(void* const* d_in, const int* in_sizes, int n_in,
                              void* d_out, int out_size, void* d_ws, size_t ws_size,
                              hipStream_t stream) {
    (void)in_sizes; (void)n_in; (void)out_size; (void)ws_size;
    const float* X     = (const float*)d_in[0];
    const float* dist  = (const float*)d_in[1];
    const float* mask  = (const float*)d_in[2];
    const float* speed = (const float*)d_in[3];
    const float* Wq    = (const float*)d_in[4];
    const float* bq    = (const float*)d_in[5];
    const float* Wk    = (const float*)d_in[6];
    const float* bk    = (const float*)d_in[7];
    const float* Wv    = (const float*)d_in[8];
    const float* bv    = (const float*)d_in[9];
    const float* Weq   = (const float*)d_in[10];
    const float* beq   = (const float*)d_in[11];
    const float* Wd1   = (const float*)d_in[16];
    const float* bd1   = (const float*)d_in[17];
    const float* Wd2   = (const float*)d_in[18];
    const float* bd2   = (const float*)d_in[19];
    const float* lng   = (const float*)d_in[20];
    const float* lnb   = (const float*)d_in[21];
    float* out = (float*)d_out;

    char* ws = (char*)d_ws;
    int*   Kp       = (int*)(ws);
    int*   candIdx  = (int*)(ws + 256);
    float* candDist = (float*)(ws + 1024);
    float* S0       = (float*)(ws + 2048);                 // 7168 B
    float* Kc       = (float*)(ws + 16384);                // 229376 B
    float* Vc       = (float*)(ws + 245760);               // 229376 B
    unsigned short* Y   = (unsigned short*)(ws + 475136);  // 1835008 B (Y2 layout)
    unsigned short* WkT = (unsigned short*)(ws + 2310144); // 524288 B
    unsigned short* WvT = (unsigned short*)(ws + 2834432); // 524288 B

    k_pre<<<145, 256, 0, stream>>>(dist, speed, Wk, Wv, Kp, candIdx, candDist, WkT, WvT);
    k_candkv<<<dim3(CB, 8, 2), 256, 0, stream>>>(X, WkT, bk, WvT, bv, candIdx, Kc, Vc);
    k_Y<<<dim3(CB * 8, 2), 256, 0, stream>>>(Wq, bq, Weq, beq, Kc, S0, Y);
    k_attn<<<CB * (CN / RB), 512, 0, stream>>>(X, dist, mask, Wd1, bd1, Wd2, bd2, lng, lnb,
                                               Kp, candIdx, candDist, Vc, S0, Y, out);
}

// Round 12
// 99.334 us; speedup vs baseline: 2.5863x; 1.1130x over previous
//
#include <hip/hip_runtime.h>
#include <math.h>

constexpr int CB  = 16;
constexpr int CN  = 1024;
constexpr int CD  = 512;
constexpr int KM1 = 7;      // K_MAX + 1 candidate slots per batch
constexpr int RB  = 32;     // rows per k_attn block

typedef __attribute__((ext_vector_type(8))) short bf8;
typedef __attribute__((ext_vector_type(4))) float f32x4;
typedef __attribute__((ext_vector_type(4))) unsigned short us4;

__device__ inline float bf2f(unsigned short u) {
    union { unsigned int i; float f; } v; v.i = ((unsigned)u) << 16; return v.f;
}
__device__ inline unsigned short f2bf(float f) {
    union { unsigned int i; float f; } v; v.f = f;
    unsigned r = v.i + 0x7FFFu + ((v.i >> 16) & 1u);
    return (unsigned short)(r >> 16);
}
// packed f32->bf16 (RNE) via HW instruction
__device__ inline unsigned int cvtpk(float lo, float hi) {
    unsigned int r;
    asm("v_cvt_pk_bf16_f32 %0, %1, %2" : "=v"(r) : "v"(lo), "v"(hi));
    return r;
}
__device__ inline bf8 pack8(float4 x, float4 y) {
    union { bf8 v; unsigned int u[4]; } r;
    r.u[0] = cvtpk(x.x, x.y); r.u[1] = cvtpk(x.z, x.w);
    r.u[2] = cvtpk(y.x, y.y); r.u[3] = cvtpk(y.z, y.w);
    return r.v;
}
__device__ inline us4 pack4(float4 x) {
    union { us4 v; unsigned int u[2]; } r;
    r.u[0] = cvtpk(x.x, x.y); r.u[1] = cvtpk(x.z, x.w);
    return r.v;
}

// ---------------------------------------------------------------------------
// Kernel PRE: blocks 0..15 top-7 | 16..143 transW | 144 computeK |
// 145.. (optional) X2 fragment-major repack: X2[tile][s][kg][r][8] bf16.
// ---------------------------------------------------------------------------
__global__ __launch_bounds__(256) void k_pre(
    const float* __restrict__ dist, const float* __restrict__ speed,
    const float* __restrict__ Wk, const float* __restrict__ Wv,
    const float* __restrict__ X,
    int* __restrict__ Kout,
    int* __restrict__ candIdx, float* __restrict__ candDist,
    unsigned short* __restrict__ WkT, unsigned short* __restrict__ WvT,
    unsigned short* __restrict__ X2) {
    int t = threadIdx.x;
    int bid = blockIdx.x;

    if (bid < 16) {
        __shared__ float sd[64 * KM1];
        __shared__ int   si[64 * KM1];
        int b = bid;
        if (t < 64) {
            float d7[KM1]; int i7[KM1];
#pragma unroll
            for (int j = 0; j < KM1; j++) { d7[j] = 3.4e38f; i7[j] = -1; }
            for (int i = t; i < CN; i += 64) {
                float d = dist[b * CN + i];
                if (d < d7[KM1 - 1]) {
                    int p = KM1 - 1;
                    while (p > 0 && d7[p - 1] > d) {
                        d7[p] = d7[p - 1]; i7[p] = i7[p - 1]; p--;
                    }
                    d7[p] = d; i7[p] = i;
                }
            }
            for (int j = 0; j < KM1; j++) { sd[t * KM1 + j] = d7[j]; si[t * KM1 + j] = i7[j]; }
        }
        __syncthreads();
        if (t == 0) {
            float m7[KM1]; int mi[KM1];
            for (int j = 0; j < KM1; j++) { m7[j] = 3.4e38f; mi[j] = -1; }
            for (int e = 0; e < 64 * KM1; e++) {
                float d = sd[e];
                if (d < m7[KM1 - 1]) {
                    int ii = si[e];
                    int p = KM1 - 1;
                    while (p > 0 && m7[p - 1] > d) {
                        m7[p] = m7[p - 1]; mi[p] = mi[p - 1]; p--;
                    }
                    m7[p] = d; mi[p] = ii;
                }
            }
            for (int j = 0; j < KM1; j++) {
                candIdx[b * KM1 + j]  = mi[j];
                candDist[b * KM1 + j] = m7[j];
            }
        }
        return;
    }
    if (bid < 144) {
        __shared__ unsigned short tile[64][68];
        int b2 = bid - 16;
        int kt = b2 & 7, ct = (b2 >> 3) & 7, mat = b2 >> 6;
        const float* W = mat ? Wv : Wk;
        unsigned short* WT = mat ? WvT : WkT;
        int k0 = kt * 64, c0 = ct * 64;
#pragma unroll
        for (int p = 0; p < 4; p++) {
            int kr = p * 16 + (t >> 4);
            int cc = (t & 15) * 4;
            float4 v = *(const float4*)(W + (size_t)(k0 + kr) * CD + c0 + cc);
            *(us4*)&tile[kr][cc] = pack4(v);
        }
        __syncthreads();
#pragma unroll
        for (int p = 0; p < 4; p++) {
            int cr = p * 16 + (t >> 4);
            int kk = (t & 15) * 4;
            us4 o;
            o.x = tile[kk + 0][cr];
            o.y = tile[kk + 1][cr];
            o.z = tile[kk + 2][cr];
            o.w = tile[kk + 3][cr];
            *(us4*)(WT + (size_t)(c0 + cr) * CD + k0 + kk) = o;
        }
        return;
    }
    if (bid == 144) {
        __shared__ int red[256];
        int cnt = 0;
        for (int i = t; i < CB * CN; i += 256) cnt += (dist[i] < 20.0f) ? 1 : 0;
        red[t] = cnt;
        __syncthreads();
        for (int s = 128; s > 0; s >>= 1) {
            if (t < s) red[t] += red[t + s];
            __syncthreads();
        }
        if (t == 0) {
            float ss = 0.f;
            for (int i = 0; i < CB; i++) ss += speed[i];
            int K = 4;
            if (ss / (float)CB > 15.0f) K = (K + 1 > 6) ? 6 : K + 1;
            float density = (float)red[0] / (float)(CB * CN);
            if (density > 0.5f) K = (K + 1 > 6) ? 6 : K + 1;
            if (K > CN - 1) K = CN - 1;
            if (K < 0) K = 0;
            *Kout = K;
        }
        return;
    }
    // ---- X2 repack (bid >= 145): one block per 32-row tile
    {
        __shared__ unsigned short sX[RB][520];
        int tileId = bid - 145;                  // 0..511 == k_attn blockIdx.x
        int b = tileId >> 5, rblk = tileId & 31;
        int row0 = b * CN + rblk * RB;
        for (int idx = t; idx < RB * 128; idx += 256) {
            int r = idx >> 7, c4 = idx & 127;
            float4 xv = *(const float4*)(X + (size_t)(row0 + r) * CD + c4 * 4);
            *(us4*)&sX[r][c4 * 4] = pack4(xv);
        }
        __syncthreads();
        unsigned short* dst = X2 + (size_t)tileId * 16384;
#pragma unroll
        for (int it = 0; it < 8; it++) {
            int unit = t + it * 256;            // unit = s*128 + kg*32 + r
            int r = unit & 31, kg = (unit >> 5) & 3, s = unit >> 7;
            const unsigned short* src = &sX[r][s * 32 + kg * 8];
            us4 lo = *(const us4*)src;
            us4 hi = *(const us4*)(src + 4);
            *(us4*)(dst + (size_t)unit * 8)     = lo;
            *(us4*)(dst + (size_t)unit * 8 + 4) = hi;
        }
    }
}

// ---------------------------------------------------------------------------
// Kernel MID (merged): bid<128 -> Vc blocks (b,ny); bid>=128 -> Y blocks
// (b,h,half) which recompute their 7x64 Kc slice locally (no global Kc).
// ---------------------------------------------------------------------------
__global__ __launch_bounds__(256) void k_mid(
    const float* __restrict__ X,
    const unsigned short* __restrict__ WkT, const float* __restrict__ bk,
    const unsigned short* __restrict__ WvT, const float* __restrict__ bv,
    const float* __restrict__ Wq, const float* __restrict__ bq,
    const float* __restrict__ Weq, const float* __restrict__ beq,
    const int* __restrict__ candIdx,
    float* __restrict__ Vc, float* __restrict__ S0,
    unsigned short* __restrict__ Y) {
    int t = threadIdx.x;
    int bid = blockIdx.x;
    __shared__ unsigned short sA[16][520];     // Xc bf16

    int b = (bid < 128) ? (bid >> 3) : ((bid - 128) >> 4);
    // stage candidate rows
    for (int i = t; i < 16 * 128; i += 256) {
        int m = i >> 7, c4 = i & 127;
        float4 xv = {0.f, 0.f, 0.f, 0.f};
        if (m < KM1)
            xv = *(const float4*)(X + (size_t)(b * CN + candIdx[b * KM1 + m]) * CD + c4 * 4);
        *(us4*)&sA[m][c4 * 4] = pack4(xv);
    }
    __syncthreads();

    int w = t >> 6, lane = t & 63, lr = lane & 15, kg = lane >> 4;

    if (bid < 128) {
        // ---- Vc block: cols ny*64 + w*16 + lr
        int ny = bid & 7;
        int c = ny * 64 + w * 16 + lr;
        const unsigned short* wtp = WvT + (size_t)c * CD + kg * 8;
        f32x4 acc = {0.f, 0.f, 0.f, 0.f};
#pragma unroll
        for (int s = 0; s < 16; s++) {
            bf8 bfr = *(const bf8*)(wtp + s * 32);
            bf8 a   = *(const bf8*)&sA[lr][s * 32 + kg * 8];
            acc = __builtin_amdgcn_mfma_f32_16x16x32_bf16(a, bfr, acc, 0, 0, 0);
        }
        float bv_ = bv[c];
#pragma unroll
        for (int q = 0; q < 4; q++) {
            int m = kg * 4 + q;
            if (m < KM1)
                Vc[(size_t)(b * KM1 + m) * CD + c] = acc[q] + bv_;
        }
        return;
    }

    // ---- Y block: (b, h, half); recompute Kc slice [7x64] for head h
    int rem = (bid - 128) & 15;
    int h = rem >> 1, half = rem & 1;
    __shared__ unsigned short sKc16[16][68];
    __shared__ float sKcf[KM1][64];

    {
        int c = h * 64 + w * 16 + lr;           // global col
        const unsigned short* wtp = WkT + (size_t)c * CD + kg * 8;
        f32x4 acc = {0.f, 0.f, 0.f, 0.f};
#pragma unroll
        for (int s = 0; s < 16; s++) {
            bf8 bfr = *(const bf8*)(wtp + s * 32);
            bf8 a   = *(const bf8*)&sA[lr][s * 32 + kg * 8];
            acc = __builtin_amdgcn_mfma_f32_16x16x32_bf16(a, bfr, acc, 0, 0, 0);
        }
        float bk_ = bk[c];
        int cl = w * 16 + lr;
#pragma unroll
        for (int q = 0; q < 4; q++) {
            int m = kg * 4 + q;
            float val = (m < KM1) ? (acc[q] + bk_) : 0.f;
            sKc16[m][cl] = f2bf(val);
            if (m < KM1) sKcf[m][cl] = val;
        }
        // zero pad rows 7..15 handled by (m<KM1)?:0 above for m in range;
        // rows beyond kg*4+3 (i.e., m 8..15 when kg<2) are covered since
        // kg spans 0..3 -> m spans 0..15. OK.
    }
    __syncthreads();

    if (half == 0 && t < 14) {
        int mat = t / 7, m = t % 7;
        const float* bias = mat ? beq : bq;
        float s = 0.f;
        for (int c = 0; c < 64; c++) s = fmaf(bias[h * 64 + c], sKcf[m][c], s);
        S0[((b * 2 + mat) * KM1 + m) * 8 + h] = s;
    }

    bf8 a0 = *(const bf8*)&sKc16[lr][kg * 8];
    bf8 a1 = *(const bf8*)&sKc16[lr][32 + kg * 8];
    unsigned short* Y2b = Y + (size_t)b * 64 * 112 * 8;
#pragma unroll
    for (int mat = 0; mat < 2; mat++) {
        const float* W = mat ? Weq : Wq;
#pragma unroll
        for (int nt = 0; nt < 4; nt++) {
            int n0 = (half * 16 + w * 4 + nt) * 16;   // k_out tile base
            const float* wp = W + (size_t)(n0 + lr) * CD + h * 64 + kg * 8;
            float4 f0 = *(const float4*)(wp);
            float4 f1 = *(const float4*)(wp + 4);
            float4 f2 = *(const float4*)(wp + 32);
            float4 f3 = *(const float4*)(wp + 36);
            f32x4 acc = {0.f, 0.f, 0.f, 0.f};
            acc = __builtin_amdgcn_mfma_f32_16x16x32_bf16(a0, pack8(f0, f1), acc, 0, 0, 0);
            acc = __builtin_amdgcn_mfma_f32_16x16x32_bf16(a1, pack8(f2, f3), acc, 0, 0, 0);
            int k_out = n0 + lr;
            int k8 = k_out >> 3, krem = k_out & 7;
#pragma unroll
            for (int q = 0; q < 4; q++) {
                int m = kg * 4 + q;
                if (m < KM1) {
                    int n = mat * 56 + m * 8 + h;
                    Y2b[((size_t)k8 * 112 + n) * 8 + krem] = f2bf(acc[q]);
                }
            }
        }
    }
}

// ---------------------------------------------------------------------------
// Kernel attn: 512 threads/block, 32 rows/block, grid 512.
//   Waves 0-3: score MFMA (B1, A-frags from X2 if available).
//   Waves 4-7: bias MLP (B2) concurrent.
//   Then blend+softmax+W7 aggregate; PV fixed-7 loop + residual + LN.
// ---------------------------------------------------------------------------
__global__ __launch_bounds__(512) void k_attn(
    const float* __restrict__ X, const float* __restrict__ dist,
    const float* __restrict__ mask,
    const float* __restrict__ Wd1, const float* __restrict__ bd1,
    const float* __restrict__ Wd2, const float* __restrict__ bd2,
    const float* __restrict__ lng, const float* __restrict__ lnb,
    const int* __restrict__ Kp, const int* __restrict__ candIdx,
    const float* __restrict__ candDist,
    const float* __restrict__ Vc, const float* __restrict__ S0,
    const unsigned short* __restrict__ Y,
    const unsigned short* __restrict__ X2, int useX2,
    float* __restrict__ out) {

    __shared__ float sS[RB][116];
    __shared__ unsigned short sVc[KM1][520];
    __shared__ float sW[RB][8][6];
    __shared__ float sW7[RB][8][8];
    __shared__ float sBias[RB][6][2][8];
    __shared__ int   snbr[RB][6];
    __shared__ float skd[RB][6];
    __shared__ float srd[RB];
    __shared__ float sE[RB];
    __shared__ float sS0[112];

    int t = threadIdx.x;
    int b = blockIdx.x >> 5, rblk = blockIdx.x & 31;
    int row0 = b * CN + rblk * RB;
    int K = *Kp;

    for (int idx = t; idx < KM1 * 128; idx += 512) {
        int m = idx >> 7, c4 = idx & 127;
        float4 vv = *(const float4*)(Vc + ((size_t)(b * KM1 + m)) * CD + c4 * 4);
        *(us4*)&sVc[m][c4 * 4] = pack4(vv);
    }
    if (t < 112) sS0[t] = S0[b * 112 + t];
    if (t < RB) {
        int i = rblk * RB + t;
        sE[t]  = mask[b * CN + i];
        srd[t] = dist[b * CN + i];
        int cnt = 0;
        for (int m = 0; m <= K && cnt < K; m++) {
            int c = candIdx[b * KM1 + m];
            if (c != i) { snbr[t][cnt] = m; skd[t][cnt] = candDist[b * KM1 + m]; cnt++; }
        }
    }
    __syncthreads();

    int w = t >> 6;
    if (w < 4) {
        int lane = t & 63, lr = lane & 15, kg = lane >> 4;
        f32x4 acc00 = {0.f, 0.f, 0.f, 0.f}, acc10 = acc00, acc01 = acc00, acc11 = acc00;
        bool has2 = (w < 3);
        const unsigned short* ypk = Y + ((size_t)b * 64 * 112 + (size_t)kg * 112 + (w * 16 + lr)) * 8;
        if (useX2) {
            const unsigned short* x2s = X2 + (size_t)blockIdx.x * 16384 + kg * 256 + lr * 8;
#pragma unroll
            for (int s = 0; s < 16; s++) {
                const unsigned short* xp = x2s + s * 1024;
                bf8 a0 = *(const bf8*)xp;
                bf8 a1 = *(const bf8*)(xp + 128);
                const unsigned short* ys = ypk + (size_t)s * 4 * 112 * 8;
                bf8 b0 = *(const bf8*)ys;
                acc00 = __builtin_amdgcn_mfma_f32_16x16x32_bf16(a0, b0, acc00, 0, 0, 0);
                acc10 = __builtin_amdgcn_mfma_f32_16x16x32_bf16(a1, b0, acc10, 0, 0, 0);
                if (has2) {
                    bf8 b1 = *(const bf8*)(ys + 512);
                    acc01 = __builtin_amdgcn_mfma_f32_16x16x32_bf16(a0, b1, acc01, 0, 0, 0);
                    acc11 = __builtin_amdgcn_mfma_f32_16x16x32_bf16(a1, b1, acc11, 0, 0, 0);
                }
            }
        } else {
            const float* x0 = X + (size_t)(row0 + lr) * CD + kg * 8;
            const float* x1 = X + (size_t)(row0 + 16 + lr) * CD + kg * 8;
#pragma unroll
            for (int s = 0; s < 16; s++) {
                int k0 = s * 32;
                float4 xa0 = *(const float4*)(x0 + k0);
                float4 xb0 = *(const float4*)(x0 + k0 + 4);
                float4 xa1 = *(const float4*)(x1 + k0);
                float4 xb1 = *(const float4*)(x1 + k0 + 4);
                bf8 a0 = pack8(xa0, xb0);
                bf8 a1 = pack8(xa1, xb1);
                const unsigned short* ys = ypk + (size_t)s * 4 * 112 * 8;
                bf8 b0 = *(const bf8*)ys;
                acc00 = __builtin_amdgcn_mfma_f32_16x16x32_bf16(a0, b0, acc00, 0, 0, 0);
                acc10 = __builtin_amdgcn_mfma_f32_16x16x32_bf16(a1, b0, acc10, 0, 0, 0);
                if (has2) {
                    bf8 b1 = *(const bf8*)(ys + 512);
                    acc01 = __builtin_amdgcn_mfma_f32_16x16x32_bf16(a0, b1, acc01, 0, 0, 0);
                    acc11 = __builtin_amdgcn_mfma_f32_16x16x32_bf16(a1, b1, acc11, 0, 0, 0);
                }
            }
        }
        int n0 = w * 16 + lr;
#pragma unroll
        for (int q = 0; q < 4; q++) {
            sS[kg * 4 + q][n0]      = acc00[q];
            sS[16 + kg * 4 + q][n0] = acc10[q];
        }
        if (has2) {
            int n1 = (w + 4) * 16 + lr;
#pragma unroll
            for (int q = 0; q < 4; q++) {
                sS[kg * 4 + q][n1]      = acc01[q];
                sS[16 + kg * 4 + q][n1] = acc11[q];
            }
        }
    } else {
        int tot2 = RB * K * 2;
        for (int task = t - 256; task < tot2; task += 256) {
            int half = task & 1;
            int pid = task >> 1;
            int r = pid / K, k = pid - r * K;
            int j0 = half * 64;
            float qd = srd[r], kd = skd[r][k];
            float bacc[8];
#pragma unroll
            for (int h = 0; h < 8; h++) bacc[h] = 0.f;
            for (int j = j0; j < j0 + 64; j++) {
                float hid = fmaf(qd, Wd1[j], fmaf(kd, Wd1[128 + j], bd1[j]));
                hid = fmaxf(hid, 0.f);
                float4 wa = *(const float4*)(Wd2 + j * 8);
                float4 wb = *(const float4*)(Wd2 + j * 8 + 4);
                bacc[0] = fmaf(hid, wa.x, bacc[0]);
                bacc[1] = fmaf(hid, wa.y, bacc[1]);
                bacc[2] = fmaf(hid, wa.z, bacc[2]);
                bacc[3] = fmaf(hid, wa.w, bacc[3]);
                bacc[4] = fmaf(hid, wb.x, bacc[4]);
                bacc[5] = fmaf(hid, wb.y, bacc[5]);
                bacc[6] = fmaf(hid, wb.z, bacc[6]);
                bacc[7] = fmaf(hid, wb.w, bacc[7]);
            }
#pragma unroll
            for (int h = 0; h < 8; h++) sBias[r][k][half][h] = bacc[h];
        }
    }
    __syncthreads();

    {
        int tot = RB * 8 * K;
        for (int id = t; id < tot; id += 512) {
            int k = id % K; int rh = id / K; int r = rh >> 3, h = rh & 7;
            int m = snbr[r][k];
            float e = sE[r];
            float scq = sS[r][m * 8 + h]      + sS0[m * 8 + h];
            float sce = sS[r][56 + m * 8 + h] + sS0[56 + m * 8 + h];
            float sc = (1.f - e) * scq + e * sce;
            float bias = sBias[r][k][0][h] + sBias[r][k][1][h] + bd2[h];
            sW[r][h][k] = sc * 0.125f * bias;
        }
    }
    __syncthreads();

    if (t < RB * 8) {
        int r = t >> 3, h = t & 7;
        float mx = -3.4e38f;
        for (int k = 0; k < K; k++) mx = fmaxf(mx, sW[r][h][k]);
        float sum = 0.f;
        for (int k = 0; k < K; k++) {
            float w0 = __expf(sW[r][h][k] - mx);
            sW[r][h][k] = w0;
            sum += w0;
        }
        float inv = 1.f / sum;
        float w7[KM1];
#pragma unroll
        for (int m = 0; m < KM1; m++) w7[m] = 0.f;
        for (int k = 0; k < K; k++) w7[snbr[r][k]] += sW[r][h][k] * inv;
#pragma unroll
        for (int m = 0; m < KM1; m++) sW7[r][h][m] = w7[m];
    }
    __syncthreads();

    {
        int r = t >> 4, tr = t & 15;
        const float* xrow = X + (size_t)(row0 + r) * CD;
        float4 vals[8];
        float sum = 0.f, sq = 0.f;
#pragma unroll
        for (int j = 0; j < 8; j++) {
            int d = tr * 4 + j * 64;    // head h = j
            float ax = 0.f, ay = 0.f, az = 0.f, aw = 0.f;
#pragma unroll
            for (int m = 0; m < KM1; m++) {
                float wgt = sW7[r][j][m];
                us4 vv = *(const us4*)&sVc[m][d];
                ax = fmaf(wgt, bf2f(vv.x), ax);
                ay = fmaf(wgt, bf2f(vv.y), ay);
                az = fmaf(wgt, bf2f(vv.z), az);
                aw = fmaf(wgt, bf2f(vv.w), aw);
            }
            float4 xv = *(const float4*)(xrow + d);
            float4 v;
            v.x = xv.x + ax; v.y = xv.y + ay; v.z = xv.z + az; v.w = xv.w + aw;
            vals[j] = v;
            sum += v.x + v.y + v.z + v.w;
            sq = fmaf(v.x, v.x, sq); sq = fmaf(v.y, v.y, sq);
            sq = fmaf(v.z, v.z, sq); sq = fmaf(v.w, v.w, sq);
        }
        sum += __shfl_xor(sum, 1, 16); sq += __shfl_xor(sq, 1, 16);
        sum += __shfl_xor(sum, 2, 16); sq += __shfl_xor(sq, 2, 16);
        sum += __shfl_xor(sum, 4, 16); sq += __shfl_xor(sq, 4, 16);
        sum += __shfl_xor(sum, 8, 16); sq += __shfl_xor(sq, 8, 16);
        float mu  = sum * (1.f / 512.f);
        float var = sq * (1.f / 512.f) - mu * mu;
        float inv = rsqrtf(var + 1e-5f);
        float* orow = out + (size_t)(row0 + r) * CD;
#pragma unroll
        for (int j = 0; j < 8; j++) {
            int d = tr * 4 + j * 64;
            float4 g  = *(const float4*)(lng + d);
            float4 bb = *(const float4*)(lnb + d);
            float4 v = vals[j];
            float4 o;
            o.x = (v.x - mu) * inv * g.x + bb.x;
            o.y = (v.y - mu) * inv * g.y + bb.y;
            o.z = (v.z - mu) * inv * g.z + bb.z;
            o.w = (v.w - mu) * inv * g.w + bb.w;
            *(float4*)(orow + d) = o;
        }
    }
}

// ---------------------------------------------------------------------------
extern "C" void kernel_launch(void* const* d_in, const int* in_sizes, int n_in,
                              void* d_out, int out_size, void* d_ws, size_t ws_size,
                              hipStream_t stream) {
    (void)in_sizes; (void)n_in; (void)out_size;
    const float* X     = (const float*)d_in[0];
    const float* dist  = (const float*)d_in[1];
    const float* mask  = (const float*)d_in[2];
    const float* speed = (const float*)d_in[3];
    const float* Wq    = (const float*)d_in[4];
    const float* bq    = (const float*)d_in[5];
    const float* Wk    = (const float*)d_in[6];
    const float* bk    = (const float*)d_in[7];
    const float* Wv    = (const float*)d_in[8];
    const float* bv    = (const float*)d_in[9];
    const float* Weq   = (const float*)d_in[10];
    const float* beq   = (const float*)d_in[11];
    const float* Wd1   = (const float*)d_in[16];
    const float* bd1   = (const float*)d_in[17];
    const float* Wd2   = (const float*)d_in[18];
    const float* bd2   = (const float*)d_in[19];
    const float* lng   = (const float*)d_in[20];
    const float* lnb   = (const float*)d_in[21];
    float* out = (float*)d_out;

    char* ws = (char*)d_ws;
    int*   Kp       = (int*)(ws);
    int*   candIdx  = (int*)(ws + 256);
    float* candDist = (float*)(ws + 1024);
    float* S0       = (float*)(ws + 2048);                 // 7168 B
    float* Vc       = (float*)(ws + 245760);               // 229376 B
    unsigned short* Y   = (unsigned short*)(ws + 475136);  // 1835008 B (Y2 layout)
    unsigned short* WkT = (unsigned short*)(ws + 2310144); // 524288 B
    unsigned short* WvT = (unsigned short*)(ws + 2834432); // 524288 B
    unsigned short* X2  = (unsigned short*)(ws + 3358720); // 16777216 B (optional)
    int useX2 = (ws_size >= (size_t)3358720 + 16777216) ? 1 : 0;

    int preBlocks = 145 + (useX2 ? 512 : 0);
    k_pre<<<preBlocks, 256, 0, stream>>>(dist, speed, Wk, Wv, X, Kp,
                                         candIdx, candDist, WkT, WvT, X2);
    k_mid<<<384, 256, 0, stream>>>(X, WkT, bk, WvT, bv, Wq, bq, Weq, beq,
                                   candIdx, Vc, S0, Y);
    k_attn<<<CB * (CN / RB), 512, 0, stream>>>(X, dist, mask, Wd1, bd1, Wd2, bd2, lng, lnb,
                                               Kp, candIdx, candDist, Vc, S0, Y,
                                               X2, useX2, out);
}

// Round 13
// 72.789 us; speedup vs baseline: 3.5295x; 1.3647x over previous
//
#include <hip/hip_runtime.h>
#include <math.h>

constexpr int CB  = 16;
constexpr int CN  = 1024;
constexpr int CD  = 512;
constexpr int KM1 = 7;      // K_MAX + 1 candidate slots per batch
constexpr int RB  = 32;     // rows per k_attn block

typedef __attribute__((ext_vector_type(8))) short bf8;
typedef __attribute__((ext_vector_type(4))) float f32x4;
typedef __attribute__((ext_vector_type(4))) unsigned short us4;

__device__ inline float bf2f(unsigned short u) {
    union { unsigned int i; float f; } v; v.i = ((unsigned)u) << 16; return v.f;
}
__device__ inline unsigned short f2bf(float f) {
    union { unsigned int i; float f; } v; v.f = f;
    unsigned r = v.i + 0x7FFFu + ((v.i >> 16) & 1u);
    return (unsigned short)(r >> 16);
}
// packed f32->bf16 (RNE) via HW instruction
__device__ inline unsigned int cvtpk(float lo, float hi) {
    unsigned int r;
    asm("v_cvt_pk_bf16_f32 %0, %1, %2" : "=v"(r) : "v"(lo), "v"(hi));
    return r;
}
__device__ inline bf8 pack8(float4 x, float4 y) {
    union { bf8 v; unsigned int u[4]; } r;
    r.u[0] = cvtpk(x.x, x.y); r.u[1] = cvtpk(x.z, x.w);
    r.u[2] = cvtpk(y.x, y.y); r.u[3] = cvtpk(y.z, y.w);
    return r.v;
}
__device__ inline us4 pack4(float4 x) {
    union { us4 v; unsigned int u[2]; } r;
    r.u[0] = cvtpk(x.x, x.y); r.u[1] = cvtpk(x.z, x.w);
    return r.v;
}

// ---------------------------------------------------------------------------
// Kernel PRE: blocks 0..15 top-7 (wave-parallel packed-min, no scratch) |
// 16..143 transW | 144 computeK | 145.. X2 fragment-major repack.
// ---------------------------------------------------------------------------
__global__ __launch_bounds__(256) void k_pre(
    const float* __restrict__ dist, const float* __restrict__ speed,
    const float* __restrict__ Wk, const float* __restrict__ Wv,
    const float* __restrict__ X,
    int* __restrict__ Kout,
    int* __restrict__ candIdx, float* __restrict__ candDist,
    unsigned short* __restrict__ WkT, unsigned short* __restrict__ WvT,
    unsigned short* __restrict__ X2) {
    int t = threadIdx.x;
    int bid = blockIdx.x;

    if (bid < 16) {
        // ---- top-7: 7 rounds of packed (dist_bits, idx) min-reduce
        __shared__ float sdist[CN];
        __shared__ unsigned long long red64[4];
        int b = bid;
        for (int i = t; i < CN; i += 256) sdist[i] = dist[b * CN + i];
        __syncthreads();
        for (int sel = 0; sel < KM1; sel++) {
            unsigned long long best = 0xFFFFFFFFFFFFFFFFull;
            for (int i = t; i < CN; i += 256) {
                unsigned long long key =
                    ((unsigned long long)__float_as_uint(sdist[i]) << 32) | (unsigned)i;
                best = best < key ? best : key;
            }
#pragma unroll
            for (int off = 32; off; off >>= 1) {
                unsigned long long o = __shfl_xor(best, off);
                best = best < o ? best : o;
            }
            if ((t & 63) == 0) red64[t >> 6] = best;
            __syncthreads();
            if (t == 0) {
                unsigned long long m0 = red64[0] < red64[1] ? red64[0] : red64[1];
                unsigned long long m1 = red64[2] < red64[3] ? red64[2] : red64[3];
                unsigned long long m = m0 < m1 ? m0 : m1;
                int idx = (int)(unsigned)(m & 0xFFFFFFFFu);
                candIdx[b * KM1 + sel]  = idx;
                candDist[b * KM1 + sel] = __uint_as_float((unsigned)(m >> 32));
                sdist[idx] = 3.4e38f;
            }
            __syncthreads();
        }
        return;
    }
    if (bid < 144) {
        __shared__ unsigned short tile[64][68];
        int b2 = bid - 16;
        int kt = b2 & 7, ct = (b2 >> 3) & 7, mat = b2 >> 6;
        const float* W = mat ? Wv : Wk;
        unsigned short* WT = mat ? WvT : WkT;
        int k0 = kt * 64, c0 = ct * 64;
#pragma unroll
        for (int p = 0; p < 4; p++) {
            int kr = p * 16 + (t >> 4);
            int cc = (t & 15) * 4;
            float4 v = *(const float4*)(W + (size_t)(k0 + kr) * CD + c0 + cc);
            *(us4*)&tile[kr][cc] = pack4(v);
        }
        __syncthreads();
#pragma unroll
        for (int p = 0; p < 4; p++) {
            int cr = p * 16 + (t >> 4);
            int kk = (t & 15) * 4;
            us4 o;
            o.x = tile[kk + 0][cr];
            o.y = tile[kk + 1][cr];
            o.z = tile[kk + 2][cr];
            o.w = tile[kk + 3][cr];
            *(us4*)(WT + (size_t)(c0 + cr) * CD + k0 + kk) = o;
        }
        return;
    }
    if (bid == 144) {
        __shared__ int red[256];
        int cnt = 0;
        for (int i = t; i < CB * CN; i += 256) cnt += (dist[i] < 20.0f) ? 1 : 0;
        red[t] = cnt;
        __syncthreads();
        for (int s = 128; s > 0; s >>= 1) {
            if (t < s) red[t] += red[t + s];
            __syncthreads();
        }
        if (t == 0) {
            float ss = 0.f;
            for (int i = 0; i < CB; i++) ss += speed[i];
            int K = 4;
            if (ss / (float)CB > 15.0f) K = (K + 1 > 6) ? 6 : K + 1;
            float density = (float)red[0] / (float)(CB * CN);
            if (density > 0.5f) K = (K + 1 > 6) ? 6 : K + 1;
            if (K > CN - 1) K = CN - 1;
            if (K < 0) K = 0;
            *Kout = K;
        }
        return;
    }
    // ---- X2 repack (bid >= 145): one block per 32-row tile
    {
        __shared__ unsigned short sX[RB][520];
        int tileId = bid - 145;                  // 0..511 == k_attn blockIdx.x
        int b = tileId >> 5, rblk = tileId & 31;
        int row0 = b * CN + rblk * RB;
        for (int idx = t; idx < RB * 128; idx += 256) {
            int r = idx >> 7, c4 = idx & 127;
            float4 xv = *(const float4*)(X + (size_t)(row0 + r) * CD + c4 * 4);
            *(us4*)&sX[r][c4 * 4] = pack4(xv);
        }
        __syncthreads();
        unsigned short* dst = X2 + (size_t)tileId * 16384;
#pragma unroll
        for (int it = 0; it < 8; it++) {
            int unit = t + it * 256;            // unit = s*128 + kg*32 + r
            int r = unit & 31, kg = (unit >> 5) & 3, s = unit >> 7;
            const unsigned short* src = &sX[r][s * 32 + kg * 8];
            us4 lo = *(const us4*)src;
            us4 hi = *(const us4*)(src + 4);
            *(us4*)(dst + (size_t)unit * 8)     = lo;
            *(us4*)(dst + (size_t)unit * 8 + 4) = hi;
        }
    }
}

// ---------------------------------------------------------------------------
// Kernel MID (merged): bid<128 -> Vc blocks (b,ny); bid>=128 -> Y blocks
// (b,h,half) which recompute their 7x64 Kc slice locally (no global Kc).
// ---------------------------------------------------------------------------
__global__ __launch_bounds__(256) void k_mid(
    const float* __restrict__ X,
    const unsigned short* __restrict__ WkT, const float* __restrict__ bk,
    const unsigned short* __restrict__ WvT, const float* __restrict__ bv,
    const float* __restrict__ Wq, const float* __restrict__ bq,
    const float* __restrict__ Weq, const float* __restrict__ beq,
    const int* __restrict__ candIdx,
    float* __restrict__ Vc, float* __restrict__ S0,
    unsigned short* __restrict__ Y) {
    int t = threadIdx.x;
    int bid = blockIdx.x;
    __shared__ unsigned short sA[16][520];     // Xc bf16

    int b = (bid < 128) ? (bid >> 3) : ((bid - 128) >> 4);
    for (int i = t; i < 16 * 128; i += 256) {
        int m = i >> 7, c4 = i & 127;
        float4 xv = {0.f, 0.f, 0.f, 0.f};
        if (m < KM1)
            xv = *(const float4*)(X + (size_t)(b * CN + candIdx[b * KM1 + m]) * CD + c4 * 4);
        *(us4*)&sA[m][c4 * 4] = pack4(xv);
    }
    __syncthreads();

    int w = t >> 6, lane = t & 63, lr = lane & 15, kg = lane >> 4;

    if (bid < 128) {
        int ny = bid & 7;
        int c = ny * 64 + w * 16 + lr;
        const unsigned short* wtp = WvT + (size_t)c * CD + kg * 8;
        f32x4 acc = {0.f, 0.f, 0.f, 0.f};
#pragma unroll
        for (int s = 0; s < 16; s++) {
            bf8 bfr = *(const bf8*)(wtp + s * 32);
            bf8 a   = *(const bf8*)&sA[lr][s * 32 + kg * 8];
            acc = __builtin_amdgcn_mfma_f32_16x16x32_bf16(a, bfr, acc, 0, 0, 0);
        }
        float bv_ = bv[c];
#pragma unroll
        for (int q = 0; q < 4; q++) {
            int m = kg * 4 + q;
            if (m < KM1)
                Vc[(size_t)(b * KM1 + m) * CD + c] = acc[q] + bv_;
        }
        return;
    }

    int rem = (bid - 128) & 15;
    int h = rem >> 1, half = rem & 1;
    __shared__ unsigned short sKc16[16][68];
    __shared__ float sKcf[KM1][64];

    {
        int c = h * 64 + w * 16 + lr;
        const unsigned short* wtp = WkT + (size_t)c * CD + kg * 8;
        f32x4 acc = {0.f, 0.f, 0.f, 0.f};
#pragma unroll
        for (int s = 0; s < 16; s++) {
            bf8 bfr = *(const bf8*)(wtp + s * 32);
            bf8 a   = *(const bf8*)&sA[lr][s * 32 + kg * 8];
            acc = __builtin_amdgcn_mfma_f32_16x16x32_bf16(a, bfr, acc, 0, 0, 0);
        }
        float bk_ = bk[c];
        int cl = w * 16 + lr;
#pragma unroll
        for (int q = 0; q < 4; q++) {
            int m = kg * 4 + q;
            float val = (m < KM1) ? (acc[q] + bk_) : 0.f;
            sKc16[m][cl] = f2bf(val);
            if (m < KM1) sKcf[m][cl] = val;
        }
    }
    __syncthreads();

    if (half == 0 && t < 14) {
        int mat = t / 7, m = t % 7;
        const float* bias = mat ? beq : bq;
        float s = 0.f;
        for (int c = 0; c < 64; c++) s = fmaf(bias[h * 64 + c], sKcf[m][c], s);
        S0[((b * 2 + mat) * KM1 + m) * 8 + h] = s;
    }

    bf8 a0 = *(const bf8*)&sKc16[lr][kg * 8];
    bf8 a1 = *(const bf8*)&sKc16[lr][32 + kg * 8];
    unsigned short* Y2b = Y + (size_t)b * 64 * 112 * 8;
#pragma unroll
    for (int mat = 0; mat < 2; mat++) {
        const float* W = mat ? Weq : Wq;
#pragma unroll
        for (int nt = 0; nt < 4; nt++) {
            int n0 = (half * 16 + w * 4 + nt) * 16;
            const float* wp = W + (size_t)(n0 + lr) * CD + h * 64 + kg * 8;
            float4 f0 = *(const float4*)(wp);
            float4 f1 = *(const float4*)(wp + 4);
            float4 f2 = *(const float4*)(wp + 32);
            float4 f3 = *(const float4*)(wp + 36);
            f32x4 acc = {0.f, 0.f, 0.f, 0.f};
            acc = __builtin_amdgcn_mfma_f32_16x16x32_bf16(a0, pack8(f0, f1), acc, 0, 0, 0);
            acc = __builtin_amdgcn_mfma_f32_16x16x32_bf16(a1, pack8(f2, f3), acc, 0, 0, 0);
            int k_out = n0 + lr;
            int k8 = k_out >> 3, krem = k_out & 7;
#pragma unroll
            for (int q = 0; q < 4; q++) {
                int m = kg * 4 + q;
                if (m < KM1) {
                    int n = mat * 56 + m * 8 + h;
                    Y2b[((size_t)k8 * 112 + n) * 8 + krem] = f2bf(acc[q]);
                }
            }
        }
    }
}

// ---------------------------------------------------------------------------
// Kernel attn: 512 threads/block, 32 rows/block, grid 512.
//   Waves 0-3: score MFMA (B1, A-frags from X2).  Waves 4-7: bias MLP (B2).
//   Then blend+softmax+W7 (static-index aggregate); PV fixed-7 loop + LN.
// ---------------------------------------------------------------------------
__global__ __launch_bounds__(512) void k_attn(
    const float* __restrict__ X, const float* __restrict__ dist,
    const float* __restrict__ mask,
    const float* __restrict__ Wd1, const float* __restrict__ bd1,
    const float* __restrict__ Wd2, const float* __restrict__ bd2,
    const float* __restrict__ lng, const float* __restrict__ lnb,
    const int* __restrict__ Kp, const int* __restrict__ candIdx,
    const float* __restrict__ candDist,
    const float* __restrict__ Vc, const float* __restrict__ S0,
    const unsigned short* __restrict__ Y,
    const unsigned short* __restrict__ X2, int useX2,
    float* __restrict__ out) {

    __shared__ float sS[RB][116];
    __shared__ unsigned short sVc[KM1][520];
    __shared__ float sW[RB][8][6];
    __shared__ float sW7[RB][8][8];
    __shared__ float sBias[RB][6][2][8];
    __shared__ int   snbr[RB][6];
    __shared__ float skd[RB][6];
    __shared__ float srd[RB];
    __shared__ float sE[RB];
    __shared__ float sS0[112];

    int t = threadIdx.x;
    int b = blockIdx.x >> 5, rblk = blockIdx.x & 31;
    int row0 = b * CN + rblk * RB;
    int K = *Kp;

    for (int idx = t; idx < KM1 * 128; idx += 512) {
        int m = idx >> 7, c4 = idx & 127;
        float4 vv = *(const float4*)(Vc + ((size_t)(b * KM1 + m)) * CD + c4 * 4);
        *(us4*)&sVc[m][c4 * 4] = pack4(vv);
    }
    if (t < 112) sS0[t] = S0[b * 112 + t];
    if (t < RB) {
        int i = rblk * RB + t;
        sE[t]  = mask[b * CN + i];
        srd[t] = dist[b * CN + i];
        int cnt = 0;
        for (int m = 0; m <= K && cnt < K; m++) {
            int c = candIdx[b * KM1 + m];
            if (c != i) { snbr[t][cnt] = m; skd[t][cnt] = candDist[b * KM1 + m]; cnt++; }
        }
    }
    __syncthreads();

    int w = t >> 6;
    if (w < 4) {
        int lane = t & 63, lr = lane & 15, kg = lane >> 4;
        f32x4 acc00 = {0.f, 0.f, 0.f, 0.f}, acc10 = acc00, acc01 = acc00, acc11 = acc00;
        bool has2 = (w < 3);
        const unsigned short* ypk = Y + ((size_t)b * 64 * 112 + (size_t)kg * 112 + (w * 16 + lr)) * 8;
        if (useX2) {
            const unsigned short* x2s = X2 + (size_t)blockIdx.x * 16384 + kg * 256 + lr * 8;
#pragma unroll
            for (int s = 0; s < 16; s++) {
                const unsigned short* xp = x2s + s * 1024;
                bf8 a0 = *(const bf8*)xp;
                bf8 a1 = *(const bf8*)(xp + 128);
                const unsigned short* ys = ypk + (size_t)s * 4 * 112 * 8;
                bf8 b0 = *(const bf8*)ys;
                acc00 = __builtin_amdgcn_mfma_f32_16x16x32_bf16(a0, b0, acc00, 0, 0, 0);
                acc10 = __builtin_amdgcn_mfma_f32_16x16x32_bf16(a1, b0, acc10, 0, 0, 0);
                if (has2) {
                    bf8 b1 = *(const bf8*)(ys + 512);
                    acc01 = __builtin_amdgcn_mfma_f32_16x16x32_bf16(a0, b1, acc01, 0, 0, 0);
                    acc11 = __builtin_amdgcn_mfma_f32_16x16x32_bf16(a1, b1, acc11, 0, 0, 0);
                }
            }
        } else {
            const float* x0 = X + (size_t)(row0 + lr) * CD + kg * 8;
            const float* x1 = X + (size_t)(row0 + 16 + lr) * CD + kg * 8;
#pragma unroll
            for (int s = 0; s < 16; s++) {
                int k0 = s * 32;
                float4 xa0 = *(const float4*)(x0 + k0);
                float4 xb0 = *(const float4*)(x0 + k0 + 4);
                float4 xa1 = *(const float4*)(x1 + k0);
                float4 xb1 = *(const float4*)(x1 + k0 + 4);
                bf8 a0 = pack8(xa0, xb0);
                bf8 a1 = pack8(xa1, xb1);
                const unsigned short* ys = ypk + (size_t)s * 4 * 112 * 8;
                bf8 b0 = *(const bf8*)ys;
                acc00 = __builtin_amdgcn_mfma_f32_16x16x32_bf16(a0, b0, acc00, 0, 0, 0);
                acc10 = __builtin_amdgcn_mfma_f32_16x16x32_bf16(a1, b0, acc10, 0, 0, 0);
                if (has2) {
                    bf8 b1 = *(const bf8*)(ys + 512);
                    acc01 = __builtin_amdgcn_mfma_f32_16x16x32_bf16(a0, b1, acc01, 0, 0, 0);
                    acc11 = __builtin_amdgcn_mfma_f32_16x16x32_bf16(a1, b1, acc11, 0, 0, 0);
                }
            }
        }
        int n0 = w * 16 + lr;
#pragma unroll
        for (int q = 0; q < 4; q++) {
            sS[kg * 4 + q][n0]      = acc00[q];
            sS[16 + kg * 4 + q][n0] = acc10[q];
        }
        if (has2) {
            int n1 = (w + 4) * 16 + lr;
#pragma unroll
            for (int q = 0; q < 4; q++) {
                sS[kg * 4 + q][n1]      = acc01[q];
                sS[16 + kg * 4 + q][n1] = acc11[q];
            }
        }
    } else {
        int tot2 = RB * K * 2;
        for (int task = t - 256; task < tot2; task += 256) {
            int half = task & 1;
            int pid = task >> 1;
            int r = pid / K, k = pid - r * K;
            int j0 = half * 64;
            float qd = srd[r], kd = skd[r][k];
            float bacc[8];
#pragma unroll
            for (int h = 0; h < 8; h++) bacc[h] = 0.f;
            for (int j = j0; j < j0 + 64; j++) {
                float hid = fmaf(qd, Wd1[j], fmaf(kd, Wd1[128 + j], bd1[j]));
                hid = fmaxf(hid, 0.f);
                float4 wa = *(const float4*)(Wd2 + j * 8);
                float4 wb = *(const float4*)(Wd2 + j * 8 + 4);
                bacc[0] = fmaf(hid, wa.x, bacc[0]);
                bacc[1] = fmaf(hid, wa.y, bacc[1]);
                bacc[2] = fmaf(hid, wa.z, bacc[2]);
                bacc[3] = fmaf(hid, wa.w, bacc[3]);
                bacc[4] = fmaf(hid, wb.x, bacc[4]);
                bacc[5] = fmaf(hid, wb.y, bacc[5]);
                bacc[6] = fmaf(hid, wb.z, bacc[6]);
                bacc[7] = fmaf(hid, wb.w, bacc[7]);
            }
#pragma unroll
            for (int h = 0; h < 8; h++) sBias[r][k][half][h] = bacc[h];
        }
    }
    __syncthreads();

    {
        int tot = RB * 8 * K;
        for (int id = t; id < tot; id += 512) {
            int k = id % K; int rh = id / K; int r = rh >> 3, h = rh & 7;
            int m = snbr[r][k];
            float e = sE[r];
            float scq = sS[r][m * 8 + h]      + sS0[m * 8 + h];
            float sce = sS[r][56 + m * 8 + h] + sS0[56 + m * 8 + h];
            float sc = (1.f - e) * scq + e * sce;
            float bias = sBias[r][k][0][h] + sBias[r][k][1][h] + bd2[h];
            sW[r][h][k] = sc * 0.125f * bias;
        }
    }
    __syncthreads();

    if (t < RB * 8) {
        int r = t >> 3, h = t & 7;
        float mx = -3.4e38f;
        for (int k = 0; k < K; k++) mx = fmaxf(mx, sW[r][h][k]);
        float sum = 0.f;
        for (int k = 0; k < K; k++) {
            float w0 = __expf(sW[r][h][k] - mx);
            sW[r][h][k] = w0;
            sum += w0;
        }
        float inv = 1.f / sum;
        // static-index slot aggregation (no scratch scatter)
#pragma unroll
        for (int m = 0; m < KM1; m++) {
            float acc = 0.f;
#pragma unroll
            for (int k = 0; k < 6; k++) {
                bool use = (k < K) && (snbr[r][k] == m);
                acc += use ? sW[r][h][k] * inv : 0.f;
            }
            sW7[r][h][m] = acc;
        }
    }
    __syncthreads();

    {
        int r = t >> 4, tr = t & 15;
        const float* xrow = X + (size_t)(row0 + r) * CD;
        float4 vals[8];
        float sum = 0.f, sq = 0.f;
#pragma unroll
        for (int j = 0; j < 8; j++) {
            int d = tr * 4 + j * 64;    // head h = j
            float ax = 0.f, ay = 0.f, az = 0.f, aw = 0.f;
#pragma unroll
            for (int m = 0; m < KM1; m++) {
                float wgt = sW7[r][j][m];
                us4 vv = *(const us4*)&sVc[m][d];
                ax = fmaf(wgt, bf2f(vv.x), ax);
                ay = fmaf(wgt, bf2f(vv.y), ay);
                az = fmaf(wgt, bf2f(vv.z), az);
                aw = fmaf(wgt, bf2f(vv.w), aw);
            }
            float4 xv = *(const float4*)(xrow + d);
            float4 v;
            v.x = xv.x + ax; v.y = xv.y + ay; v.z = xv.z + az; v.w = xv.w + aw;
            vals[j] = v;
            sum += v.x + v.y + v.z + v.w;
            sq = fmaf(v.x, v.x, sq); sq = fmaf(v.y, v.y, sq);
            sq = fmaf(v.z, v.z, sq); sq = fmaf(v.w, v.w, sq);
        }
        sum += __shfl_xor(sum, 1, 16); sq += __shfl_xor(sq, 1, 16);
        sum += __shfl_xor(sum, 2, 16); sq += __shfl_xor(sq, 2, 16);
        sum += __shfl_xor(sum, 4, 16); sq += __shfl_xor(sq, 4, 16);
        sum += __shfl_xor(sum, 8, 16); sq += __shfl_xor(sq, 8, 16);
        float mu  = sum * (1.f / 512.f);
        float var = sq * (1.f / 512.f) - mu * mu;
        float inv = rsqrtf(var + 1e-5f);
        float* orow = out + (size_t)(row0 + r) * CD;
#pragma unroll
        for (int j = 0; j < 8; j++) {
            int d = tr * 4 + j * 64;
            float4 g  = *(const float4*)(lng + d);
            float4 bb = *(const float4*)(lnb + d);
            float4 v = vals[j];
            float4 o;
            o.x = (v.x - mu) * inv * g.x + bb.x;
            o.y = (v.y - mu) * inv * g.y + bb.y;
            o.z = (v.z - mu) * inv * g.z + bb.z;
            o.w = (v.w - mu) * inv * g.w + bb.w;
            *(float4*)(orow + d) = o;
        }
    }
}

// ---------------------------------------------------------------------------
extern "C" void kernel_launch(void* const* d_in, const int* in_sizes, int n_in,
                              void* d_out, int out_size, void* d_ws, size_t ws_size,
                              hipStream_t stream) {
    (void)in_sizes; (void)n_in; (void)out_size;
    const float* X     = (const float*)d_in[0];
    const float* dist  = (const float*)d_in[1];
    const float* mask  = (const float*)d_in[2];
    const float* speed = (const float*)d_in[3];
    const float* Wq    = (const float*)d_in[4];
    const float* bq    = (const float*)d_in[5];
    const float* Wk    = (const float*)d_in[6];
    const float* bk    = (const float*)d_in[7];
    const float* Wv    = (const float*)d_in[8];
    const float* bv    = (const float*)d_in[9];
    const float* Weq   = (const float*)d_in[10];
    const float* beq   = (const float*)d_in[11];
    const float* Wd1   = (const float*)d_in[16];
    const float* bd1   = (const float*)d_in[17];
    const float* Wd2   = (const float*)d_in[18];
    const float* bd2   = (const float*)d_in[19];
    const float* lng   = (const float*)d_in[20];
    const float* lnb   = (const float*)d_in[21];
    float* out = (float*)d_out;

    char* ws = (char*)d_ws;
    int*   Kp       = (int*)(ws);
    int*   candIdx  = (int*)(ws + 256);
    float* candDist = (float*)(ws + 1024);
    float* S0       = (float*)(ws + 2048);                 // 7168 B
    float* Vc       = (float*)(ws + 245760);               // 229376 B
    unsigned short* Y   = (unsigned short*)(ws + 475136);  // 1835008 B (Y2 layout)
    unsigned short* WkT = (unsigned short*)(ws + 2310144); // 524288 B
    unsigned short* WvT = (unsigned short*)(ws + 2834432); // 524288 B
    unsigned short* X2  = (unsigned short*)(ws + 3358720); // 16777216 B (optional)
    int useX2 = (ws_size >= (size_t)3358720 + 16777216) ? 1 : 0;

    int preBlocks = 145 + (useX2 ? 512 : 0);
    k_pre<<<preBlocks, 256, 0, stream>>>(dist, speed, Wk, Wv, X, Kp,
                                         candIdx, candDist, WkT, WvT, X2);
    k_mid<<<384, 256, 0, stream>>>(X, WkT, bk, WvT, bv, Wq, bq, Weq, beq,
                                   candIdx, Vc, S0, Y);
    k_attn<<<CB * (CN / RB), 512, 0, stream>>>(X, dist, mask, Wd1, bd1, Wd2, bd2, lng, lnb,
                                               Kp, candIdx, candDist, Vc, S0, Y,
                                               X2, useX2, out);
}

// Round 14
// 71.529 us; speedup vs baseline: 3.5917x; 1.0176x over previous
//
#include <hip/hip_runtime.h>
#include <math.h>

constexpr int CB  = 16;
constexpr int CN  = 1024;
constexpr int CD  = 512;
constexpr int KM1 = 7;      // K_MAX + 1 candidate slots per batch
constexpr int RB  = 32;     // rows per k_attn block

typedef __attribute__((ext_vector_type(8))) short bf8;
typedef __attribute__((ext_vector_type(4))) float f32x4;
typedef __attribute__((ext_vector_type(4))) unsigned short us4;

__device__ inline float bf2f(unsigned short u) {
    union { unsigned int i; float f; } v; v.i = ((unsigned)u) << 16; return v.f;
}
__device__ inline unsigned short f2bf(float f) {
    union { unsigned int i; float f; } v; v.f = f;
    unsigned r = v.i + 0x7FFFu + ((v.i >> 16) & 1u);
    return (unsigned short)(r >> 16);
}
// packed f32->bf16 (RNE) via HW instruction
__device__ inline unsigned int cvtpk(float lo, float hi) {
    unsigned int r;
    asm("v_cvt_pk_bf16_f32 %0, %1, %2" : "=v"(r) : "v"(lo), "v"(hi));
    return r;
}
__device__ inline bf8 pack8(float4 x, float4 y) {
    union { bf8 v; unsigned int u[4]; } r;
    r.u[0] = cvtpk(x.x, x.y); r.u[1] = cvtpk(x.z, x.w);
    r.u[2] = cvtpk(y.x, y.y); r.u[3] = cvtpk(y.z, y.w);
    return r.v;
}
__device__ inline us4 pack4(float4 x) {
    union { us4 v; unsigned int u[2]; } r;
    r.u[0] = cvtpk(x.x, x.y); r.u[1] = cvtpk(x.z, x.w);
    return r.v;
}

// ---------------------------------------------------------------------------
// Kernel PRE: blocks 0..15 top-7 (wave-parallel packed-min) |
// 16..143 transW | 144 computeK.  (X2 repack moved to k_mid.)
// ---------------------------------------------------------------------------
__global__ __launch_bounds__(256) void k_pre(
    const float* __restrict__ dist, const float* __restrict__ speed,
    const float* __restrict__ Wk, const float* __restrict__ Wv,
    int* __restrict__ Kout,
    int* __restrict__ candIdx, float* __restrict__ candDist,
    unsigned short* __restrict__ WkT, unsigned short* __restrict__ WvT) {
    int t = threadIdx.x;
    int bid = blockIdx.x;

    if (bid < 16) {
        // ---- top-7: 7 rounds of packed (dist_bits, idx) min-reduce
        __shared__ float sdist[CN];
        __shared__ unsigned long long red64[4];
        int b = bid;
        for (int i = t; i < CN; i += 256) sdist[i] = dist[b * CN + i];
        __syncthreads();
        for (int sel = 0; sel < KM1; sel++) {
            unsigned long long best = 0xFFFFFFFFFFFFFFFFull;
            for (int i = t; i < CN; i += 256) {
                unsigned long long key =
                    ((unsigned long long)__float_as_uint(sdist[i]) << 32) | (unsigned)i;
                best = best < key ? best : key;
            }
#pragma unroll
            for (int off = 32; off; off >>= 1) {
                unsigned long long o = __shfl_xor(best, off);
                best = best < o ? best : o;
            }
            if ((t & 63) == 0) red64[t >> 6] = best;
            __syncthreads();
            if (t == 0) {
                unsigned long long m0 = red64[0] < red64[1] ? red64[0] : red64[1];
                unsigned long long m1 = red64[2] < red64[3] ? red64[2] : red64[3];
                unsigned long long m = m0 < m1 ? m0 : m1;
                int idx = (int)(unsigned)(m & 0xFFFFFFFFu);
                candIdx[b * KM1 + sel]  = idx;
                candDist[b * KM1 + sel] = __uint_as_float((unsigned)(m >> 32));
                sdist[idx] = 3.4e38f;
            }
            __syncthreads();
        }
        return;
    }
    if (bid < 144) {
        __shared__ unsigned short tile[64][68];
        int b2 = bid - 16;
        int kt = b2 & 7, ct = (b2 >> 3) & 7, mat = b2 >> 6;
        const float* W = mat ? Wv : Wk;
        unsigned short* WT = mat ? WvT : WkT;
        int k0 = kt * 64, c0 = ct * 64;
#pragma unroll
        for (int p = 0; p < 4; p++) {
            int kr = p * 16 + (t >> 4);
            int cc = (t & 15) * 4;
            float4 v = *(const float4*)(W + (size_t)(k0 + kr) * CD + c0 + cc);
            *(us4*)&tile[kr][cc] = pack4(v);
        }
        __syncthreads();
#pragma unroll
        for (int p = 0; p < 4; p++) {
            int cr = p * 16 + (t >> 4);
            int kk = (t & 15) * 4;
            us4 o;
            o.x = tile[kk + 0][cr];
            o.y = tile[kk + 1][cr];
            o.z = tile[kk + 2][cr];
            o.w = tile[kk + 3][cr];
            *(us4*)(WT + (size_t)(c0 + cr) * CD + k0 + kk) = o;
        }
        return;
    }
    {
        __shared__ int red[256];
        int cnt = 0;
        for (int i = t; i < CB * CN; i += 256) cnt += (dist[i] < 20.0f) ? 1 : 0;
        red[t] = cnt;
        __syncthreads();
        for (int s = 128; s > 0; s >>= 1) {
            if (t < s) red[t] += red[t + s];
            __syncthreads();
        }
        if (t == 0) {
            float ss = 0.f;
            for (int i = 0; i < CB; i++) ss += speed[i];
            int K = 4;
            if (ss / (float)CB > 15.0f) K = (K + 1 > 6) ? 6 : K + 1;
            float density = (float)red[0] / (float)(CB * CN);
            if (density > 0.5f) K = (K + 1 > 6) ? 6 : K + 1;
            if (K > CN - 1) K = CN - 1;
            if (K < 0) K = 0;
            *Kout = K;
        }
    }
}

// ---------------------------------------------------------------------------
// Kernel MID (merged): bid<128 -> Vc blocks (b,ny); 128..383 -> Y blocks
// (b,h,half) which recompute their 7x64 Kc slice locally; bid>=384 ->
// X2 fragment-major repack (no dependency on k_pre outputs).
// ---------------------------------------------------------------------------
__global__ __launch_bounds__(256) void k_mid(
    const float* __restrict__ X,
    const unsigned short* __restrict__ WkT, const float* __restrict__ bk,
    const unsigned short* __restrict__ WvT, const float* __restrict__ bv,
    const float* __restrict__ Wq, const float* __restrict__ bq,
    const float* __restrict__ Weq, const float* __restrict__ beq,
    const int* __restrict__ candIdx,
    float* __restrict__ Vc, float* __restrict__ S0,
    unsigned short* __restrict__ Y,
    unsigned short* __restrict__ X2) {
    int t = threadIdx.x;
    int bid = blockIdx.x;
    __shared__ unsigned short sbuf[RB][520];   // repack: 32 rows; Vc/Y: rows 0..15

    if (bid >= 384) {
        // ---- X2 repack: one block per 32-row tile
        int tileId = bid - 384;                  // 0..511 == k_attn blockIdx.x
        int b = tileId >> 5, rblk = tileId & 31;
        int row0 = b * CN + rblk * RB;
        for (int idx = t; idx < RB * 128; idx += 256) {
            int r = idx >> 7, c4 = idx & 127;
            float4 xv = *(const float4*)(X + (size_t)(row0 + r) * CD + c4 * 4);
            *(us4*)&sbuf[r][c4 * 4] = pack4(xv);
        }
        __syncthreads();
        unsigned short* dst = X2 + (size_t)tileId * 16384;
#pragma unroll
        for (int it = 0; it < 8; it++) {
            int unit = t + it * 256;            // unit = s*128 + kg*32 + r
            int r = unit & 31, kg = (unit >> 5) & 3, s = unit >> 7;
            const unsigned short* src = &sbuf[r][s * 32 + kg * 8];
            us4 lo = *(const us4*)src;
            us4 hi = *(const us4*)(src + 4);
            *(us4*)(dst + (size_t)unit * 8)     = lo;
            *(us4*)(dst + (size_t)unit * 8 + 4) = hi;
        }
        return;
    }

    int b = (bid < 128) ? (bid >> 3) : ((bid - 128) >> 4);
    for (int i = t; i < 16 * 128; i += 256) {
        int m = i >> 7, c4 = i & 127;
        float4 xv = {0.f, 0.f, 0.f, 0.f};
        if (m < KM1)
            xv = *(const float4*)(X + (size_t)(b * CN + candIdx[b * KM1 + m]) * CD + c4 * 4);
        *(us4*)&sbuf[m][c4 * 4] = pack4(xv);
    }
    __syncthreads();

    int w = t >> 6, lane = t & 63, lr = lane & 15, kg = lane >> 4;

    if (bid < 128) {
        int ny = bid & 7;
        int c = ny * 64 + w * 16 + lr;
        const unsigned short* wtp = WvT + (size_t)c * CD + kg * 8;
        f32x4 acc = {0.f, 0.f, 0.f, 0.f};
#pragma unroll
        for (int s = 0; s < 16; s++) {
            bf8 bfr = *(const bf8*)(wtp + s * 32);
            bf8 a   = *(const bf8*)&sbuf[lr][s * 32 + kg * 8];
            acc = __builtin_amdgcn_mfma_f32_16x16x32_bf16(a, bfr, acc, 0, 0, 0);
        }
        float bv_ = bv[c];
#pragma unroll
        for (int q = 0; q < 4; q++) {
            int m = kg * 4 + q;
            if (m < KM1)
                Vc[(size_t)(b * KM1 + m) * CD + c] = acc[q] + bv_;
        }
        return;
    }

    int rem = (bid - 128) & 15;
    int h = rem >> 1, half = rem & 1;
    __shared__ unsigned short sKc16[16][68];
    __shared__ float sKcf[KM1][64];

    {
        int c = h * 64 + w * 16 + lr;
        const unsigned short* wtp = WkT + (size_t)c * CD + kg * 8;
        f32x4 acc = {0.f, 0.f, 0.f, 0.f};
#pragma unroll
        for (int s = 0; s < 16; s++) {
            bf8 bfr = *(const bf8*)(wtp + s * 32);
            bf8 a   = *(const bf8*)&sbuf[lr][s * 32 + kg * 8];
            acc = __builtin_amdgcn_mfma_f32_16x16x32_bf16(a, bfr, acc, 0, 0, 0);
        }
        float bk_ = bk[c];
        int cl = w * 16 + lr;
#pragma unroll
        for (int q = 0; q < 4; q++) {
            int m = kg * 4 + q;
            float val = (m < KM1) ? (acc[q] + bk_) : 0.f;
            sKc16[m][cl] = f2bf(val);
            if (m < KM1) sKcf[m][cl] = val;
        }
    }
    __syncthreads();

    if (half == 0 && t < 14) {
        int mat = t / 7, m = t % 7;
        const float* bias = mat ? beq : bq;
        float s = 0.f;
        for (int c = 0; c < 64; c++) s = fmaf(bias[h * 64 + c], sKcf[m][c], s);
        S0[((b * 2 + mat) * KM1 + m) * 8 + h] = s;
    }

    bf8 a0 = *(const bf8*)&sKc16[lr][kg * 8];
    bf8 a1 = *(const bf8*)&sKc16[lr][32 + kg * 8];
    unsigned short* Y2b = Y + (size_t)b * 64 * 112 * 8;
#pragma unroll
    for (int mat = 0; mat < 2; mat++) {
        const float* W = mat ? Weq : Wq;
#pragma unroll
        for (int nt = 0; nt < 4; nt++) {
            int n0 = (half * 16 + w * 4 + nt) * 16;
            const float* wp = W + (size_t)(n0 + lr) * CD + h * 64 + kg * 8;
            float4 f0 = *(const float4*)(wp);
            float4 f1 = *(const float4*)(wp + 4);
            float4 f2 = *(const float4*)(wp + 32);
            float4 f3 = *(const float4*)(wp + 36);
            f32x4 acc = {0.f, 0.f, 0.f, 0.f};
            acc = __builtin_amdgcn_mfma_f32_16x16x32_bf16(a0, pack8(f0, f1), acc, 0, 0, 0);
            acc = __builtin_amdgcn_mfma_f32_16x16x32_bf16(a1, pack8(f2, f3), acc, 0, 0, 0);
            int k_out = n0 + lr;
            int k8 = k_out >> 3, krem = k_out & 7;
#pragma unroll
            for (int q = 0; q < 4; q++) {
                int m = kg * 4 + q;
                if (m < KM1) {
                    int n = mat * 56 + m * 8 + h;
                    Y2b[((size_t)k8 * 112 + n) * 8 + krem] = f2bf(acc[q]);
                }
            }
        }
    }
}

// ---------------------------------------------------------------------------
// Kernel attn: 512 threads/block, 32 rows/block, grid 512.
//   Waves 0-3: score MFMA (B1, A-frags from X2).  Waves 4-7: bias MLP (B2).
//   Fused blend+softmax+W7 in registers (phase D); PV fixed-7 loop + LN.
//   3 barriers total.
// ---------------------------------------------------------------------------
__global__ __launch_bounds__(512) void k_attn(
    const float* __restrict__ X, const float* __restrict__ dist,
    const float* __restrict__ mask,
    const float* __restrict__ Wd1, const float* __restrict__ bd1,
    const float* __restrict__ Wd2, const float* __restrict__ bd2,
    const float* __restrict__ lng, const float* __restrict__ lnb,
    const int* __restrict__ Kp, const int* __restrict__ candIdx,
    const float* __restrict__ candDist,
    const float* __restrict__ Vc, const float* __restrict__ S0,
    const unsigned short* __restrict__ Y,
    const unsigned short* __restrict__ X2, int useX2,
    float* __restrict__ out) {

    __shared__ float sS[RB][116];
    __shared__ unsigned short sVc[KM1][520];
    __shared__ float sW7[RB][8][8];
    __shared__ float sBias[RB][6][2][8];
    __shared__ int   snbr[RB][6];
    __shared__ float skd[RB][6];
    __shared__ float srd[RB];
    __shared__ float sE[RB];
    __shared__ float sS0[112];

    int t = threadIdx.x;
    int b = blockIdx.x >> 5, rblk = blockIdx.x & 31;
    int row0 = b * CN + rblk * RB;
    int K = *Kp;

    for (int idx = t; idx < KM1 * 128; idx += 512) {
        int m = idx >> 7, c4 = idx & 127;
        float4 vv = *(const float4*)(Vc + ((size_t)(b * KM1 + m)) * CD + c4 * 4);
        *(us4*)&sVc[m][c4 * 4] = pack4(vv);
    }
    if (t < 112) sS0[t] = S0[b * 112 + t];
    if (t < RB) {
        int i = rblk * RB + t;
        sE[t]  = mask[b * CN + i];
        srd[t] = dist[b * CN + i];
        int cnt = 0;
        for (int m = 0; m <= K && cnt < K; m++) {
            int c = candIdx[b * KM1 + m];
            if (c != i) { snbr[t][cnt] = m; skd[t][cnt] = candDist[b * KM1 + m]; cnt++; }
        }
    }
    __syncthreads();

    int w = t >> 6;
    if (w < 4) {
        int lane = t & 63, lr = lane & 15, kg = lane >> 4;
        f32x4 acc00 = {0.f, 0.f, 0.f, 0.f}, acc10 = acc00, acc01 = acc00, acc11 = acc00;
        bool has2 = (w < 3);
        const unsigned short* ypk = Y + ((size_t)b * 64 * 112 + (size_t)kg * 112 + (w * 16 + lr)) * 8;
        if (useX2) {
            const unsigned short* x2s = X2 + (size_t)blockIdx.x * 16384 + kg * 256 + lr * 8;
#pragma unroll
            for (int s = 0; s < 16; s++) {
                const unsigned short* xp = x2s + s * 1024;
                bf8 a0 = *(const bf8*)xp;
                bf8 a1 = *(const bf8*)(xp + 128);
                const unsigned short* ys = ypk + (size_t)s * 4 * 112 * 8;
                bf8 b0 = *(const bf8*)ys;
                acc00 = __builtin_amdgcn_mfma_f32_16x16x32_bf16(a0, b0, acc00, 0, 0, 0);
                acc10 = __builtin_amdgcn_mfma_f32_16x16x32_bf16(a1, b0, acc10, 0, 0, 0);
                if (has2) {
                    bf8 b1 = *(const bf8*)(ys + 512);
                    acc01 = __builtin_amdgcn_mfma_f32_16x16x32_bf16(a0, b1, acc01, 0, 0, 0);
                    acc11 = __builtin_amdgcn_mfma_f32_16x16x32_bf16(a1, b1, acc11, 0, 0, 0);
                }
            }
        } else {
            const float* x0 = X + (size_t)(row0 + lr) * CD + kg * 8;
            const float* x1 = X + (size_t)(row0 + 16 + lr) * CD + kg * 8;
#pragma unroll
            for (int s = 0; s < 16; s++) {
                int k0 = s * 32;
                float4 xa0 = *(const float4*)(x0 + k0);
                float4 xb0 = *(const float4*)(x0 + k0 + 4);
                float4 xa1 = *(const float4*)(x1 + k0);
                float4 xb1 = *(const float4*)(x1 + k0 + 4);
                bf8 a0 = pack8(xa0, xb0);
                bf8 a1 = pack8(xa1, xb1);
                const unsigned short* ys = ypk + (size_t)s * 4 * 112 * 8;
                bf8 b0 = *(const bf8*)ys;
                acc00 = __builtin_amdgcn_mfma_f32_16x16x32_bf16(a0, b0, acc00, 0, 0, 0);
                acc10 = __builtin_amdgcn_mfma_f32_16x16x32_bf16(a1, b0, acc10, 0, 0, 0);
                if (has2) {
                    bf8 b1 = *(const bf8*)(ys + 512);
                    acc01 = __builtin_amdgcn_mfma_f32_16x16x32_bf16(a0, b1, acc01, 0, 0, 0);
                    acc11 = __builtin_amdgcn_mfma_f32_16x16x32_bf16(a1, b1, acc11, 0, 0, 0);
                }
            }
        }
        int n0 = w * 16 + lr;
#pragma unroll
        for (int q = 0; q < 4; q++) {
            sS[kg * 4 + q][n0]      = acc00[q];
            sS[16 + kg * 4 + q][n0] = acc10[q];
        }
        if (has2) {
            int n1 = (w + 4) * 16 + lr;
#pragma unroll
            for (int q = 0; q < 4; q++) {
                sS[kg * 4 + q][n1]      = acc01[q];
                sS[16 + kg * 4 + q][n1] = acc11[q];
            }
        }
    } else {
        int tot2 = RB * K * 2;
        for (int task = t - 256; task < tot2; task += 256) {
            int half = task & 1;
            int pid = task >> 1;
            int r = pid / K, k = pid - r * K;
            int j0 = half * 64;
            float qd = srd[r], kd = skd[r][k];
            float bacc[8];
#pragma unroll
            for (int h = 0; h < 8; h++) bacc[h] = 0.f;
            for (int j = j0; j < j0 + 64; j++) {
                float hid = fmaf(qd, Wd1[j], fmaf(kd, Wd1[128 + j], bd1[j]));
                hid = fmaxf(hid, 0.f);
                float4 wa = *(const float4*)(Wd2 + j * 8);
                float4 wb = *(const float4*)(Wd2 + j * 8 + 4);
                bacc[0] = fmaf(hid, wa.x, bacc[0]);
                bacc[1] = fmaf(hid, wa.y, bacc[1]);
                bacc[2] = fmaf(hid, wa.z, bacc[2]);
                bacc[3] = fmaf(hid, wa.w, bacc[3]);
                bacc[4] = fmaf(hid, wb.x, bacc[4]);
                bacc[5] = fmaf(hid, wb.y, bacc[5]);
                bacc[6] = fmaf(hid, wb.z, bacc[6]);
                bacc[7] = fmaf(hid, wb.w, bacc[7]);
            }
#pragma unroll
            for (int h = 0; h < 8; h++) sBias[r][k][half][h] = bacc[h];
        }
    }
    __syncthreads();

    // ---- phase D (fused blend + softmax + W7, all in registers)
    if (t < RB * 8) {
        int r = t >> 3, h = t & 7;
        float e = sE[r];
        float wv[6];
#pragma unroll
        for (int k = 0; k < 6; k++) {
            if (k < K) {
                int m = snbr[r][k];
                float scq = sS[r][m * 8 + h]      + sS0[m * 8 + h];
                float sce = sS[r][56 + m * 8 + h] + sS0[56 + m * 8 + h];
                float sc = (1.f - e) * scq + e * sce;
                float bias = sBias[r][k][0][h] + sBias[r][k][1][h] + bd2[h];
                wv[k] = sc * 0.125f * bias;
            } else {
                wv[k] = -3.4e38f;
            }
        }
        float mx = -3.4e38f;
#pragma unroll
        for (int k = 0; k < 6; k++) mx = fmaxf(mx, wv[k]);
        float sum = 0.f;
#pragma unroll
        for (int k = 0; k < 6; k++) {
            wv[k] = __expf(wv[k] - mx);
            sum += wv[k];
        }
        float inv = 1.f / sum;
#pragma unroll
        for (int m = 0; m < KM1; m++) {
            float acc = 0.f;
#pragma unroll
            for (int k = 0; k < 6; k++) {
                bool use = (k < K) && (snbr[r][k] == m);
                acc += use ? wv[k] * inv : 0.f;
            }
            sW7[r][h][m] = acc;
        }
    }
    __syncthreads();

    // ---- phase E: PV (fixed 7-slot loop) + residual + LN (16 thr/row, h=j)
    {
        int r = t >> 4, tr = t & 15;
        const float* xrow = X + (size_t)(row0 + r) * CD;
        float4 vals[8];
        float sum = 0.f, sq = 0.f;
#pragma unroll
        for (int j = 0; j < 8; j++) {
            int d = tr * 4 + j * 64;    // head h = j
            float ax = 0.f, ay = 0.f, az = 0.f, aw = 0.f;
#pragma unroll
            for (int m = 0; m < KM1; m++) {
                float wgt = sW7[r][j][m];
                us4 vv = *(const us4*)&sVc[m][d];
                ax = fmaf(wgt, bf2f(vv.x), ax);
                ay = fmaf(wgt, bf2f(vv.y), ay);
                az = fmaf(wgt, bf2f(vv.z), az);
                aw = fmaf(wgt, bf2f(vv.w), aw);
            }
            float4 xv = *(const float4*)(xrow + d);
            float4 v;
            v.x = xv.x + ax; v.y = xv.y + ay; v.z = xv.z + az; v.w = xv.w + aw;
            vals[j] = v;
            sum += v.x + v.y + v.z + v.w;
            sq = fmaf(v.x, v.x, sq); sq = fmaf(v.y, v.y, sq);
            sq = fmaf(v.z, v.z, sq); sq = fmaf(v.w, v.w, sq);
        }
        sum += __shfl_xor(sum, 1, 16); sq += __shfl_xor(sq, 1, 16);
        sum += __shfl_xor(sum, 2, 16); sq += __shfl_xor(sq, 2, 16);
        sum += __shfl_xor(sum, 4, 16); sq += __shfl_xor(sq, 4, 16);
        sum += __shfl_xor(sum, 8, 16); sq += __shfl_xor(sq, 8, 16);
        float mu  = sum * (1.f / 512.f);
        float var = sq * (1.f / 512.f) - mu * mu;
        float inv = rsqrtf(var + 1e-5f);
        float* orow = out + (size_t)(row0 + r) * CD;
#pragma unroll
        for (int j = 0; j < 8; j++) {
            int d = tr * 4 + j * 64;
            float4 g  = *(const float4*)(lng + d);
            float4 bb = *(const float4*)(lnb + d);
            float4 v = vals[j];
            float4 o;
            o.x = (v.x - mu) * inv * g.x + bb.x;
            o.y = (v.y - mu) * inv * g.y + bb.y;
            o.z = (v.z - mu) * inv * g.z + bb.z;
            o.w = (v.w - mu) * inv * g.w + bb.w;
            *(float4*)(orow + d) = o;
        }
    }
}

// ---------------------------------------------------------------------------
extern "C" void kernel_launch(void* const* d_in, const int* in_sizes, int n_in,
                              void* d_out, int out_size, void* d_ws, size_t ws_size,
                              hipStream_t stream) {
    (void)in_sizes; (void)n_in; (void)out_size;
    const float* X     = (const float*)d_in[0];
    const float* dist  = (const float*)d_in[1];
    const float* mask  = (const float*)d_in[2];
    const float* speed = (const float*)d_in[3];
    const float* Wq    = (const float*)d_in[4];
    const float* bq    = (const float*)d_in[5];
    const float* Wk    = (const float*)d_in[6];
    const float* bk    = (const float*)d_in[7];
    const float* Wv    = (const float*)d_in[8];
    const float* bv    = (const float*)d_in[9];
    const float* Weq   = (const float*)d_in[10];
    const float* beq   = (const float*)d_in[11];
    const float* Wd1   = (const float*)d_in[16];
    const float* bd1   = (const float*)d_in[17];
    const float* Wd2   = (const float*)d_in[18];
    const float* bd2   = (const float*)d_in[19];
    const float* lng   = (const float*)d_in[20];
    const float* lnb   = (const float*)d_in[21];
    float* out = (float*)d_out;

    char* ws = (char*)d_ws;
    int*   Kp       = (int*)(ws);
    int*   candIdx  = (int*)(ws + 256);
    float* candDist = (float*)(ws + 1024);
    float* S0       = (float*)(ws + 2048);                 // 7168 B
    float* Vc       = (float*)(ws + 245760);               // 229376 B
    unsigned short* Y   = (unsigned short*)(ws + 475136);  // 1835008 B (Y2 layout)
    unsigned short* WkT = (unsigned short*)(ws + 2310144); // 524288 B
    unsigned short* WvT = (unsigned short*)(ws + 2834432); // 524288 B
    unsigned short* X2  = (unsigned short*)(ws + 3358720); // 16777216 B (optional)
    int useX2 = (ws_size >= (size_t)3358720 + 16777216) ? 1 : 0;

    k_pre<<<145, 256, 0, stream>>>(dist, speed, Wk, Wv, Kp, candIdx, candDist, WkT, WvT);
    int midBlocks = 384 + (useX2 ? 512 : 0);
    k_mid<<<midBlocks, 256, 0, stream>>>(X, WkT, bk, WvT, bv, Wq, bq, Weq, beq,
                                         candIdx, Vc, S0, Y, X2);
    k_attn<<<CB * (CN / RB), 512, 0, stream>>>(X, dist, mask, Wd1, bd1, Wd2, bd2, lng, lnb,
                                               Kp, candIdx, candDist, Vc, S0, Y,
                                               X2, useX2, out);
}